// Round 3
// baseline (1125.291 us; speedup 1.0000x reference)
//
#include <hip/hip_runtime.h>

#define N_NODES 50000
#define N_EDGES 800000
#define DIM 128
#define NLAYERS 4
#define BN_EPS 1e-5f

// ---------------- prep kernels ----------------

__global__ __launch_bounds__(256) void k_zero(int* __restrict__ p, int n){
    int i = blockIdx.x * 256 + threadIdx.x;
    if (i < n) p[i] = 0;
}

__global__ __launch_bounds__(256) void k_count(const int* __restrict__ dst,
                                               int* __restrict__ degcnt){
    int e = blockIdx.x * 256 + threadIdx.x;
    if (e < N_EDGES) atomicAdd(&degcnt[dst[e]], 1);
}

__global__ __launch_bounds__(256) void k_dis(const int* __restrict__ degcnt,
                                             float* __restrict__ dis){
    int i = blockIdx.x * 256 + threadIdx.x;
    if (i < N_NODES) dis[i] = rsqrtf((float)degcnt[i] + 1.0f);
}

// single-block 256-thread chunked exclusive scan: degcnt -> rowptr (+wptr copy)
__global__ __launch_bounds__(256) void k_scan(const int* __restrict__ degcnt,
                                              int* __restrict__ rowptr,
                                              int* __restrict__ wptr){
    __shared__ int sums[256];
    const int CH = (N_NODES + 255) / 256;            // 196
    int t = threadIdx.x;
    int lo = t * CH;
    int hi = lo + CH; if (hi > N_NODES) hi = N_NODES;
    int s = 0;
    for (int i = lo; i < hi; i++) s += degcnt[i];
    sums[t] = s;
    __syncthreads();
    for (int off = 1; off < 256; off <<= 1){
        int v = (t >= off) ? sums[t - off] : 0;
        __syncthreads();
        sums[t] += v;
        __syncthreads();
    }
    int run = (t == 0) ? 0 : sums[t - 1];
    for (int i = lo; i < hi; i++){
        rowptr[i] = run; wptr[i] = run;
        run += degcnt[i];
    }
    if (t == 255) rowptr[N_NODES] = run;
}

__global__ __launch_bounds__(256) void k_fill(const int* __restrict__ src,
                                              const int* __restrict__ dst,
                                              int* __restrict__ wptr,
                                              int* __restrict__ esrc){
    int e = blockIdx.x * 256 + threadIdx.x;
    if (e < N_EDGES){
        int d = dst[e];
        int p = atomicAdd(&wptr[d], 1);
        esrc[p] = src[e];
    }
}

// ---------------- per-layer kernels ----------------

// h = z @ W  (z fp32 [N,128], W fp32 [128,128] row-major [k][c], h fp32)
// 32 rows/block, 256 threads, 4x4 micro-tile. LDS: 16KB z tile. W via L1/L2.
__global__ __launch_bounds__(256) void k_gemm(const float* __restrict__ z,
                                              const float* __restrict__ W,
                                              float* __restrict__ h){
    __shared__ float zs[32][DIM];              // 16 KB
    int tid = threadIdx.x;
    int row0 = blockIdx.x * 32;

    const float4* zv = (const float4*)z;
    float4* zsv = (float4*)(&zs[0][0]);
    #pragma unroll
    for (int i = 0; i < 4; i++){
        int idx = tid + 256*i;                 // float4 units within tile
        int r = idx >> 5;                      // 32 float4 per row
        float4 val = make_float4(0.f, 0.f, 0.f, 0.f);
        if (row0 + r < N_NODES) val = zv[row0*32 + idx];
        zsv[idx] = val;
    }
    __syncthreads();

    int r0 = (tid >> 5) * 4;                   // 8 row groups
    int c0 = (tid & 31) * 4;                   // 32 col groups
    float acc[4][4] = {};

    for (int k = 0; k < DIM; k += 4){
        float4 a[4];
        #pragma unroll
        for (int r = 0; r < 4; r++) a[r] = *(const float4*)&zs[r0 + r][k];
        float4 wv[4];
        #pragma unroll
        for (int kk = 0; kk < 4; kk++)
            wv[kk] = *(const float4*)&W[(k + kk)*DIM + c0];
        #pragma unroll
        for (int r = 0; r < 4; r++){
            float av[4] = {a[r].x, a[r].y, a[r].z, a[r].w};
            #pragma unroll
            for (int kk = 0; kk < 4; kk++){
                acc[r][0] = fmaf(av[kk], wv[kk].x, acc[r][0]);
                acc[r][1] = fmaf(av[kk], wv[kk].y, acc[r][1]);
                acc[r][2] = fmaf(av[kk], wv[kk].z, acc[r][2]);
                acc[r][3] = fmaf(av[kk], wv[kk].w, acc[r][3]);
            }
        }
    }
    #pragma unroll
    for (int r = 0; r < 4; r++){
        int row = row0 + r0 + r;
        if (row < N_NODES)
            *(float4*)&h[row*DIM + c0] =
                make_float4(acc[r][0], acc[r][1], acc[r][2], acc[r][3]);
    }
}

// CSR aggregation + bias + ReLU + per-column sum/sumsq partials.
// One wave per node, lane holds cols (2*lane, 2*lane+1) as float2.
__global__ __launch_bounds__(256) void k_agg(const float* __restrict__ h,
                                             const int* __restrict__ rowptr,
                                             const int* __restrict__ esrc,
                                             const float* __restrict__ dis,
                                             const float* __restrict__ bias,
                                             float* __restrict__ out,
                                             float* __restrict__ stats){
    int lane = threadIdx.x & 63;
    int w    = threadIdx.x >> 6;
    const float2* h2 = (const float2*)h;
    float2* o2 = (float2*)out;
    float b0 = bias[2*lane], b1 = bias[2*lane + 1];
    float s0 = 0.f, s1 = 0.f, q0 = 0.f, q1 = 0.f;

    for (int node = blockIdx.x*4 + w; node < N_NODES; node += gridDim.x*4){
        float di = dis[node];
        int e0 = rowptr[node], e1 = rowptr[node + 1];
        float2 hv = h2[node*64 + lane];
        float dii = di * di;
        float a0 = hv.x * dii, a1 = hv.y * dii;
        for (int e = e0; e < e1; e++){
            int s = esrc[e];
            float we = dis[s] * di;
            float2 hs = h2[s*64 + lane];
            a0 = fmaf(hs.x, we, a0);
            a1 = fmaf(hs.y, we, a1);
        }
        a0 += b0; a1 += b1;
        a0 = fmaxf(a0, 0.f); a1 = fmaxf(a1, 0.f);
        o2[node*64 + lane] = make_float2(a0, a1);
        s0 += a0; s1 += a1; q0 += a0*a0; q1 += a1*a1;
    }

    __shared__ float red[4][64][4];
    red[w][lane][0] = s0; red[w][lane][1] = s1;
    red[w][lane][2] = q0; red[w][lane][3] = q1;
    __syncthreads();
    if (w == 0){
        #pragma unroll
        for (int ww = 1; ww < 4; ww++){
            s0 += red[ww][lane][0]; s1 += red[ww][lane][1];
            q0 += red[ww][lane][2]; q1 += red[ww][lane][3];
        }
        atomicAdd(&stats[2*lane],       s0);
        atomicAdd(&stats[2*lane + 1],   s1);
        atomicAdd(&stats[DIM + 2*lane],     q0);
        atomicAdd(&stats[DIM + 2*lane + 1], q1);
    }
}

__global__ void k_bnstat(const float* __restrict__ stats, float* __restrict__ musig){
    int c = threadIdx.x;
    float mu  = stats[c] * (1.0f / N_NODES);
    float var = stats[DIM + c] * (1.0f / N_NODES) - mu * mu;
    musig[c] = mu;
    musig[DIM + c] = rsqrtf(var + BN_EPS);
}

// BN normalize (pure elementwise, in-place capable). out = (z-mu)*rstd*g + b
__global__ __launch_bounds__(256) void k_bn(const float4* __restrict__ in,
                                            const float* __restrict__ musig,
                                            const float* __restrict__ gamma,
                                            const float* __restrict__ beta,
                                            float4* __restrict__ outf){
    int i = blockIdx.x * 256 + threadIdx.x;         // float4 index
    if (i >= N_NODES * DIM / 4) return;
    float4 v = in[i];
    int c = (i * 4) & (DIM - 1);
    float4 mu = *(const float4*)&musig[c];
    float4 rs = *(const float4*)&musig[DIM + c];
    float4 g4 = *(const float4*)&gamma[c];
    float4 b4 = *(const float4*)&beta[c];
    float4 r;
    r.x = (v.x - mu.x) * rs.x * g4.x + b4.x;
    r.y = (v.y - mu.y) * rs.y * g4.y + b4.y;
    r.z = (v.z - mu.z) * rs.z * g4.z + b4.z;
    r.w = (v.w - mu.w) * rs.w * g4.w + b4.w;
    outf[i] = r;
}

// ---------------- launch ----------------

extern "C" void kernel_launch(void* const* d_in, const int* in_sizes, int n_in,
                              void* d_out, int out_size, void* d_ws, size_t ws_size,
                              hipStream_t stream){
    const float* x   = (const float*)d_in[0];
    const int*   src = (const int*)d_in[1];
    const int*   dst = src + N_EDGES;
    const float* Ws  = (const float*)d_in[2];
    const float* bs  = (const float*)d_in[3];
    const float* gs  = (const float*)d_in[4];
    const float* be  = (const float*)d_in[5];

    char* w = (char*)d_ws;
    int*   degcnt = (int*)(w);                  // [0, 200000)
    float* stats  = (float*)(w + 200000);       // 1024 f (4 layers x 256)
    float* musig  = (float*)(w + 204096);       // 256 f
    float* dis    = (float*)(w + 205120);       // 50000 f
    int*   rowptr = (int*)(w + 405120);         // 50001 i (pad to 605136)
    int*   wptr   = (int*)(w + 605136);         // 50000 i
    int*   esrc   = (int*)(w + 805136);         // 800000 i
    float* bufA   = (float*)(w + 4005136);      // 6.4M f  (layer in/out)
    float* bufB   = (float*)(w + 29605136);     // 6.4M f  (h)
    // total: 55,205,136 bytes

    k_zero<<<(51024 + 255)/256, 256, 0, stream>>>(degcnt, 51024);
    k_count<<<3125, 256, 0, stream>>>(dst, degcnt);
    k_dis<<<196, 256, 0, stream>>>(degcnt, dis);
    k_scan<<<1, 256, 0, stream>>>(degcnt, rowptr, wptr);
    k_fill<<<3125, 256, 0, stream>>>(src, dst, wptr, esrc);

    for (int L = 0; L < NLAYERS; L++){
        const float* zin = (L == 0) ? x : bufA;
        // zin -> bufB (h = z @ W)
        k_gemm<<<(N_NODES + 31)/32, 256, 0, stream>>>(zin, Ws + L*DIM*DIM, bufB);
        // bufB -> bufA (aggregate + bias + relu + stats)
        k_agg<<<1024, 256, 0, stream>>>(bufB, rowptr, esrc, dis, bs + L*DIM,
                                        bufA, stats + L*256);
        k_bnstat<<<1, 128, 0, stream>>>(stats + L*256, musig);
        float* bnout = (L == NLAYERS - 1) ? (float*)d_out : bufA;
        k_bn<<<6250, 256, 0, stream>>>((const float4*)bufA, musig,
                                       gs + L*DIM, be + L*DIM,
                                       (float4*)bnout);
    }
}

// Round 4
// 1074.315 us; speedup vs baseline: 1.0474x; 1.0474x over previous
//
#include <hip/hip_runtime.h>

#define N_NODES 50000
#define N_EDGES 800000
#define DIM 128
#define NLAYERS 4
#define BN_EPS 1e-5f

// ---------------- prep kernels ----------------

__global__ __launch_bounds__(256) void k_zero(int* __restrict__ p, int n){
    int i = blockIdx.x * 256 + threadIdx.x;
    if (i < n) p[i] = 0;
}

__global__ __launch_bounds__(256) void k_count(const int* __restrict__ dst,
                                               int* __restrict__ degcnt){
    int e = blockIdx.x * 256 + threadIdx.x;
    if (e < N_EDGES) atomicAdd(&degcnt[dst[e]], 1);
}

__global__ __launch_bounds__(256) void k_dis(const int* __restrict__ degcnt,
                                             float* __restrict__ dis){
    int i = blockIdx.x * 256 + threadIdx.x;
    if (i < N_NODES) dis[i] = rsqrtf((float)degcnt[i] + 1.0f);
}

// single-block 256-thread chunked exclusive scan: degcnt -> rowptr (+wptr copy)
__global__ __launch_bounds__(256) void k_scan(const int* __restrict__ degcnt,
                                              int* __restrict__ rowptr,
                                              int* __restrict__ wptr){
    __shared__ int sums[256];
    const int CH = (N_NODES + 255) / 256;            // 196
    int t = threadIdx.x;
    int lo = t * CH;
    int hi = lo + CH; if (hi > N_NODES) hi = N_NODES;
    int s = 0;
    for (int i = lo; i < hi; i++) s += degcnt[i];
    sums[t] = s;
    __syncthreads();
    for (int off = 1; off < 256; off <<= 1){
        int v = (t >= off) ? sums[t - off] : 0;
        __syncthreads();
        sums[t] += v;
        __syncthreads();
    }
    int run = (t == 0) ? 0 : sums[t - 1];
    for (int i = lo; i < hi; i++){
        rowptr[i] = run; wptr[i] = run;
        run += degcnt[i];
    }
    if (t == 255) rowptr[N_NODES] = run;
}

__global__ __launch_bounds__(256) void k_fill(const int* __restrict__ src,
                                              const int* __restrict__ dst,
                                              int* __restrict__ wptr,
                                              int* __restrict__ esrc){
    int e = blockIdx.x * 256 + threadIdx.x;
    if (e < N_EDGES){
        int d = dst[e];
        int p = atomicAdd(&wptr[d], 1);
        esrc[p] = src[e];
    }
}

// ---------------- per-layer kernels ----------------

// h = z' @ W where z' = z (BN=false) or z*sc + sh per column (BN=true).
// z fp32 [N,128], W fp32 [128,128] row-major [k][c], h fp32.
// 32 rows/block, 256 threads, 4x4 micro-tile. LDS: 16KB z tile. W via L1/L2.
template<bool BN>
__global__ __launch_bounds__(256) void k_gemm(const float* __restrict__ z,
                                              const float* __restrict__ W,
                                              const float* __restrict__ scsh,
                                              float* __restrict__ h){
    __shared__ float zs[32][DIM];              // 16 KB
    int tid = threadIdx.x;
    int row0 = blockIdx.x * 32;

    const float4* zv = (const float4*)z;
    float4* zsv = (float4*)(&zs[0][0]);
    #pragma unroll
    for (int i = 0; i < 4; i++){
        int idx = tid + 256*i;                 // float4 units within tile
        int r = idx >> 5;                      // 32 float4 per row
        float4 val = make_float4(0.f, 0.f, 0.f, 0.f);
        if (row0 + r < N_NODES) val = zv[row0*32 + idx];
        if (BN){
            int c = (idx & 31) * 4;
            float4 sc = *(const float4*)&scsh[c];
            float4 sh = *(const float4*)&scsh[DIM + c];
            val.x = fmaf(val.x, sc.x, sh.x);
            val.y = fmaf(val.y, sc.y, sh.y);
            val.z = fmaf(val.z, sc.z, sh.z);
            val.w = fmaf(val.w, sc.w, sh.w);
        }
        zsv[idx] = val;
    }
    __syncthreads();

    int r0 = (tid >> 5) * 4;                   // 8 row groups
    int c0 = (tid & 31) * 4;                   // 32 col groups
    float acc[4][4] = {};

    for (int k = 0; k < DIM; k += 4){
        float4 a[4];
        #pragma unroll
        for (int r = 0; r < 4; r++) a[r] = *(const float4*)&zs[r0 + r][k];
        float4 wv[4];
        #pragma unroll
        for (int kk = 0; kk < 4; kk++)
            wv[kk] = *(const float4*)&W[(k + kk)*DIM + c0];
        #pragma unroll
        for (int r = 0; r < 4; r++){
            float av[4] = {a[r].x, a[r].y, a[r].z, a[r].w};
            #pragma unroll
            for (int kk = 0; kk < 4; kk++){
                acc[r][0] = fmaf(av[kk], wv[kk].x, acc[r][0]);
                acc[r][1] = fmaf(av[kk], wv[kk].y, acc[r][1]);
                acc[r][2] = fmaf(av[kk], wv[kk].z, acc[r][2]);
                acc[r][3] = fmaf(av[kk], wv[kk].w, acc[r][3]);
            }
        }
    }
    #pragma unroll
    for (int r = 0; r < 4; r++){
        int row = row0 + r0 + r;
        if (row < N_NODES)
            *(float4*)&h[row*DIM + c0] =
                make_float4(acc[r][0], acc[r][1], acc[r][2], acc[r][3]);
    }
}

// CSR aggregation + bias + ReLU + per-column sum/sumsq partials.
// One wave per node, lane holds cols (2*lane, 2*lane+1) as float2.
// Edge loop unrolled x4 with independent accumulators for memory ILP.
__global__ __launch_bounds__(256) void k_agg(const float* __restrict__ h,
                                             const int* __restrict__ rowptr,
                                             const int* __restrict__ esrc,
                                             const float* __restrict__ dis,
                                             const float* __restrict__ bias,
                                             float* __restrict__ out,
                                             float* __restrict__ stats){
    int lane = threadIdx.x & 63;
    int w    = threadIdx.x >> 6;
    const float2* h2 = (const float2*)h;
    float2* o2 = (float2*)out;
    float b0 = bias[2*lane], b1 = bias[2*lane + 1];
    float s0 = 0.f, s1 = 0.f, q0 = 0.f, q1 = 0.f;

    for (int node = blockIdx.x*4 + w; node < N_NODES; node += gridDim.x*4){
        float di = dis[node];
        int e0 = rowptr[node], e1 = rowptr[node + 1];
        float2 hv = h2[node*64 + lane];
        float dii = di * di;
        float a0 = hv.x * dii, a1 = hv.y * dii;
        float c0 = 0.f, c1 = 0.f, d0 = 0.f, d1 = 0.f, f0 = 0.f, f1 = 0.f;

        int e = e0;
        for (; e + 4 <= e1; e += 4){
            int si0 = esrc[e],   si1 = esrc[e+1];
            int si2 = esrc[e+2], si3 = esrc[e+3];
            float w0 = dis[si0] * di, w1 = dis[si1] * di;
            float w2 = dis[si2] * di, w3 = dis[si3] * di;
            float2 x0 = h2[si0*64 + lane], x1 = h2[si1*64 + lane];
            float2 x2 = h2[si2*64 + lane], x3 = h2[si3*64 + lane];
            a0 = fmaf(x0.x, w0, a0); a1 = fmaf(x0.y, w0, a1);
            c0 = fmaf(x1.x, w1, c0); c1 = fmaf(x1.y, w1, c1);
            d0 = fmaf(x2.x, w2, d0); d1 = fmaf(x2.y, w2, d1);
            f0 = fmaf(x3.x, w3, f0); f1 = fmaf(x3.y, w3, f1);
        }
        for (; e < e1; e++){
            int si = esrc[e];
            float we = dis[si] * di;
            float2 xs = h2[si*64 + lane];
            a0 = fmaf(xs.x, we, a0);
            a1 = fmaf(xs.y, we, a1);
        }
        a0 += c0 + d0 + f0;
        a1 += c1 + d1 + f1;
        a0 += b0; a1 += b1;
        a0 = fmaxf(a0, 0.f); a1 = fmaxf(a1, 0.f);
        o2[node*64 + lane] = make_float2(a0, a1);
        s0 += a0; s1 += a1; q0 += a0*a0; q1 += a1*a1;
    }

    __shared__ float red[4][64][4];
    red[w][lane][0] = s0; red[w][lane][1] = s1;
    red[w][lane][2] = q0; red[w][lane][3] = q1;
    __syncthreads();
    if (w == 0){
        #pragma unroll
        for (int ww = 1; ww < 4; ww++){
            s0 += red[ww][lane][0]; s1 += red[ww][lane][1];
            q0 += red[ww][lane][2]; q1 += red[ww][lane][3];
        }
        atomicAdd(&stats[2*lane],       s0);
        atomicAdd(&stats[2*lane + 1],   s1);
        atomicAdd(&stats[DIM + 2*lane],     q0);
        atomicAdd(&stats[DIM + 2*lane + 1], q1);
    }
}

// stats -> per-column scale/shift:  sc = rstd*gamma, sh = beta - mu*sc
__global__ void k_bnstat(const float* __restrict__ stats,
                         const float* __restrict__ gamma,
                         const float* __restrict__ beta,
                         float* __restrict__ scsh){
    int c = threadIdx.x;
    float mu  = stats[c] * (1.0f / N_NODES);
    float var = stats[DIM + c] * (1.0f / N_NODES) - mu * mu;
    float sc  = rsqrtf(var + BN_EPS) * gamma[c];
    scsh[c] = sc;
    scsh[DIM + c] = beta[c] - mu * sc;
}

// final-layer BN apply: out = a*sc + sh
__global__ __launch_bounds__(256) void k_bn(const float4* __restrict__ in,
                                            const float* __restrict__ scsh,
                                            float4* __restrict__ outf){
    int i = blockIdx.x * 256 + threadIdx.x;         // float4 index
    if (i >= N_NODES * DIM / 4) return;
    float4 v = in[i];
    int c = (i * 4) & (DIM - 1);
    float4 sc = *(const float4*)&scsh[c];
    float4 sh = *(const float4*)&scsh[DIM + c];
    float4 r;
    r.x = fmaf(v.x, sc.x, sh.x);
    r.y = fmaf(v.y, sc.y, sh.y);
    r.z = fmaf(v.z, sc.z, sh.z);
    r.w = fmaf(v.w, sc.w, sh.w);
    outf[i] = r;
}

// ---------------- launch ----------------

extern "C" void kernel_launch(void* const* d_in, const int* in_sizes, int n_in,
                              void* d_out, int out_size, void* d_ws, size_t ws_size,
                              hipStream_t stream){
    const float* x   = (const float*)d_in[0];
    const int*   src = (const int*)d_in[1];
    const int*   dst = src + N_EDGES;
    const float* Ws  = (const float*)d_in[2];
    const float* bs  = (const float*)d_in[3];
    const float* gs  = (const float*)d_in[4];
    const float* be  = (const float*)d_in[5];

    char* w = (char*)d_ws;
    int*   degcnt = (int*)(w);                  // 50000 i   [0, 200000)
    float* stats  = (float*)(w + 200000);       // 1024 f (4 layers x 256)
    float* scsh   = (float*)(w + 204096);       // 1024 f (4 layers x 256)
    float* dis    = (float*)(w + 208192);       // 50000 f
    int*   rowptr = (int*)(w + 408192);         // 50001 i (pad)
    int*   wptr   = (int*)(w + 608208);         // 50000 i
    int*   esrc   = (int*)(w + 808208);         // 800000 i
    float* bufA   = (float*)(w + 4008208);      // 6.4M f  (layer in/out)
    float* bufB   = (float*)(w + 29608208);     // 6.4M f  (h)
    // total: 55,208,208 bytes

    k_zero<<<(51024 + 255)/256, 256, 0, stream>>>(degcnt, 51024);
    k_count<<<3125, 256, 0, stream>>>(dst, degcnt);
    k_dis<<<196, 256, 0, stream>>>(degcnt, dis);
    k_scan<<<1, 256, 0, stream>>>(degcnt, rowptr, wptr);
    k_fill<<<3125, 256, 0, stream>>>(src, dst, wptr, esrc);

    for (int L = 0; L < NLAYERS; L++){
        const float* zin = (L == 0) ? x : bufA;
        if (L == 0)
            k_gemm<false><<<1563, 256, 0, stream>>>(zin, Ws + L*DIM*DIM,
                                                    nullptr, bufB);
        else
            k_gemm<true><<<1563, 256, 0, stream>>>(zin, Ws + L*DIM*DIM,
                                                   scsh + (L-1)*256, bufB);
        k_agg<<<2048, 256, 0, stream>>>(bufB, rowptr, esrc, dis, bs + L*DIM,
                                        bufA, stats + L*256);
        k_bnstat<<<1, 128, 0, stream>>>(stats + L*256, gs + L*DIM, be + L*DIM,
                                        scsh + L*256);
    }
    k_bn<<<6250, 256, 0, stream>>>((const float4*)bufA, scsh + 3*256,
                                   (float4*)d_out);
}

// Round 5
// 993.806 us; speedup vs baseline: 1.1323x; 1.0810x over previous
//
#include <hip/hip_runtime.h>

#define N_NODES 50000
#define N_EDGES 800000
#define DIM 128
#define NLAYERS 4
#define BN_EPS 1e-5f

__device__ __forceinline__ float bf2f(unsigned short u){
    union { unsigned int i; float f; } x; x.i = ((unsigned int)u) << 16; return x.f;
}
__device__ __forceinline__ unsigned short f2bf(float f){
    union { float f; unsigned int i; } x; x.f = f;
    unsigned int lsb = (x.i >> 16) & 1u;
    unsigned int r = x.i + 0x7fffu + lsb;
    return (unsigned short)(r >> 16);
}

// ---------------- prep kernels ----------------

__global__ __launch_bounds__(256) void k_zero(int* __restrict__ p, int n){
    int i = blockIdx.x * 256 + threadIdx.x;
    if (i < n) p[i] = 0;
}

__global__ __launch_bounds__(256) void k_count(const int* __restrict__ dst,
                                               int* __restrict__ degcnt){
    int e = blockIdx.x * 256 + threadIdx.x;
    if (e < N_EDGES) atomicAdd(&degcnt[dst[e]], 1);
}

__global__ __launch_bounds__(256) void k_dis(const int* __restrict__ degcnt,
                                             float* __restrict__ dis){
    int i = blockIdx.x * 256 + threadIdx.x;
    if (i < N_NODES) dis[i] = rsqrtf((float)degcnt[i] + 1.0f);
}

// single-block 256-thread chunked exclusive scan: degcnt -> rowptr (+wptr copy)
__global__ __launch_bounds__(256) void k_scan(const int* __restrict__ degcnt,
                                              int* __restrict__ rowptr,
                                              int* __restrict__ wptr){
    __shared__ int sums[256];
    const int CH = (N_NODES + 255) / 256;            // 196
    int t = threadIdx.x;
    int lo = t * CH;
    int hi = lo + CH; if (hi > N_NODES) hi = N_NODES;
    int s = 0;
    for (int i = lo; i < hi; i++) s += degcnt[i];
    sums[t] = s;
    __syncthreads();
    for (int off = 1; off < 256; off <<= 1){
        int v = (t >= off) ? sums[t - off] : 0;
        __syncthreads();
        sums[t] += v;
        __syncthreads();
    }
    int run = (t == 0) ? 0 : sums[t - 1];
    for (int i = lo; i < hi; i++){
        rowptr[i] = run; wptr[i] = run;
        run += degcnt[i];
    }
    if (t == 255) rowptr[N_NODES] = run;
}

__global__ __launch_bounds__(256) void k_fill(const int* __restrict__ src,
                                              const int* __restrict__ dst,
                                              int* __restrict__ wptr,
                                              int* __restrict__ esrc){
    int e = blockIdx.x * 256 + threadIdx.x;
    if (e < N_EDGES){
        int d = dst[e];
        int p = atomicAdd(&wptr[d], 1);
        esrc[p] = src[e];
    }
}

// ---------------- per-layer kernels ----------------

// h = z' @ W where z' = z (BN=false) or z*sc + sh per column (BN=true).
// z fp32 [N,128], W fp32 [128,128] row-major [k][c], h stored as BF16 [N,128].
// 32 rows/block, 256 threads, 4x4 micro-tile. LDS: 16KB z tile. W via L1/L2.
template<bool BN>
__global__ __launch_bounds__(256) void k_gemm(const float* __restrict__ z,
                                              const float* __restrict__ W,
                                              const float* __restrict__ scsh,
                                              unsigned short* __restrict__ hb){
    __shared__ float zs[32][DIM];              // 16 KB
    int tid = threadIdx.x;
    int row0 = blockIdx.x * 32;

    const float4* zv = (const float4*)z;
    float4* zsv = (float4*)(&zs[0][0]);
    #pragma unroll
    for (int i = 0; i < 4; i++){
        int idx = tid + 256*i;                 // float4 units within tile
        int r = idx >> 5;                      // 32 float4 per row
        float4 val = make_float4(0.f, 0.f, 0.f, 0.f);
        if (row0 + r < N_NODES) val = zv[row0*32 + idx];
        if (BN){
            int c = (idx & 31) * 4;
            float4 sc = *(const float4*)&scsh[c];
            float4 sh = *(const float4*)&scsh[DIM + c];
            val.x = fmaf(val.x, sc.x, sh.x);
            val.y = fmaf(val.y, sc.y, sh.y);
            val.z = fmaf(val.z, sc.z, sh.z);
            val.w = fmaf(val.w, sc.w, sh.w);
        }
        zsv[idx] = val;
    }
    __syncthreads();

    int r0 = (tid >> 5) * 4;                   // 8 row groups
    int c0 = (tid & 31) * 4;                   // 32 col groups
    float acc[4][4] = {};

    for (int k = 0; k < DIM; k += 4){
        float4 a[4];
        #pragma unroll
        for (int r = 0; r < 4; r++) a[r] = *(const float4*)&zs[r0 + r][k];
        float4 wv[4];
        #pragma unroll
        for (int kk = 0; kk < 4; kk++)
            wv[kk] = *(const float4*)&W[(k + kk)*DIM + c0];
        #pragma unroll
        for (int r = 0; r < 4; r++){
            float av[4] = {a[r].x, a[r].y, a[r].z, a[r].w};
            #pragma unroll
            for (int kk = 0; kk < 4; kk++){
                acc[r][0] = fmaf(av[kk], wv[kk].x, acc[r][0]);
                acc[r][1] = fmaf(av[kk], wv[kk].y, acc[r][1]);
                acc[r][2] = fmaf(av[kk], wv[kk].z, acc[r][2]);
                acc[r][3] = fmaf(av[kk], wv[kk].w, acc[r][3]);
            }
        }
    }
    #pragma unroll
    for (int r = 0; r < 4; r++){
        int row = row0 + r0 + r;
        if (row < N_NODES){
            ushort4 o;
            o.x = f2bf(acc[r][0]); o.y = f2bf(acc[r][1]);
            o.z = f2bf(acc[r][2]); o.w = f2bf(acc[r][3]);
            *(ushort4*)&hb[row*DIM + c0] = o;
        }
    }
}

// CSR aggregation + bias + ReLU + per-column sum/sumsq partials.
// h is BF16; one wave per node, lane holds cols (2*lane, 2*lane+1) as ushort2.
// Edge loop unrolled x8, 4 independent fp32 accumulator pairs.
__global__ __launch_bounds__(256) void k_agg(const unsigned short* __restrict__ h,
                                             const int* __restrict__ rowptr,
                                             const int* __restrict__ esrc,
                                             const float* __restrict__ dis,
                                             const float* __restrict__ bias,
                                             float* __restrict__ out,
                                             float* __restrict__ stats){
    int lane = threadIdx.x & 63;
    int w    = threadIdx.x >> 6;
    const ushort2* h2 = (const ushort2*)h;
    float2* o2 = (float2*)out;
    float b0 = bias[2*lane], b1 = bias[2*lane + 1];
    float s0 = 0.f, s1 = 0.f, q0 = 0.f, q1 = 0.f;

    for (int node = blockIdx.x*4 + w; node < N_NODES; node += gridDim.x*4){
        float di = dis[node];
        int e0 = rowptr[node], e1 = rowptr[node + 1];
        ushort2 hv = h2[node*64 + lane];
        float dii = di * di;
        float p0[4] = {bf2f(hv.x) * dii, 0.f, 0.f, 0.f};
        float p1[4] = {bf2f(hv.y) * dii, 0.f, 0.f, 0.f};

        int e = e0;
        for (; e + 8 <= e1; e += 8){
            int si[8];
            #pragma unroll
            for (int j = 0; j < 8; j++) si[j] = esrc[e + j];
            float wg[8];
            #pragma unroll
            for (int j = 0; j < 8; j++) wg[j] = dis[si[j]] * di;
            ushort2 xs[8];
            #pragma unroll
            for (int j = 0; j < 8; j++) xs[j] = h2[si[j]*64 + lane];
            #pragma unroll
            for (int j = 0; j < 8; j++){
                p0[j & 3] = fmaf(bf2f(xs[j].x), wg[j], p0[j & 3]);
                p1[j & 3] = fmaf(bf2f(xs[j].y), wg[j], p1[j & 3]);
            }
        }
        for (; e < e1; e++){
            int si = esrc[e];
            float we = dis[si] * di;
            ushort2 xv = h2[si*64 + lane];
            p0[0] = fmaf(bf2f(xv.x), we, p0[0]);
            p1[0] = fmaf(bf2f(xv.y), we, p1[0]);
        }
        float a0 = (p0[0] + p0[1]) + (p0[2] + p0[3]) + b0;
        float a1 = (p1[0] + p1[1]) + (p1[2] + p1[3]) + b1;
        a0 = fmaxf(a0, 0.f); a1 = fmaxf(a1, 0.f);
        o2[node*64 + lane] = make_float2(a0, a1);
        s0 += a0; s1 += a1; q0 += a0*a0; q1 += a1*a1;
    }

    __shared__ float red[4][64][4];
    red[w][lane][0] = s0; red[w][lane][1] = s1;
    red[w][lane][2] = q0; red[w][lane][3] = q1;
    __syncthreads();
    if (w == 0){
        #pragma unroll
        for (int ww = 1; ww < 4; ww++){
            s0 += red[ww][lane][0]; s1 += red[ww][lane][1];
            q0 += red[ww][lane][2]; q1 += red[ww][lane][3];
        }
        atomicAdd(&stats[2*lane],       s0);
        atomicAdd(&stats[2*lane + 1],   s1);
        atomicAdd(&stats[DIM + 2*lane],     q0);
        atomicAdd(&stats[DIM + 2*lane + 1], q1);
    }
}

// stats -> per-column scale/shift:  sc = rstd*gamma, sh = beta - mu*sc
__global__ void k_bnstat(const float* __restrict__ stats,
                         const float* __restrict__ gamma,
                         const float* __restrict__ beta,
                         float* __restrict__ scsh){
    int c = threadIdx.x;
    float mu  = stats[c] * (1.0f / N_NODES);
    float var = stats[DIM + c] * (1.0f / N_NODES) - mu * mu;
    float sc  = rsqrtf(var + BN_EPS) * gamma[c];
    scsh[c] = sc;
    scsh[DIM + c] = beta[c] - mu * sc;
}

// final-layer BN apply: out = a*sc + sh
__global__ __launch_bounds__(256) void k_bn(const float4* __restrict__ in,
                                            const float* __restrict__ scsh,
                                            float4* __restrict__ outf){
    int i = blockIdx.x * 256 + threadIdx.x;         // float4 index
    if (i >= N_NODES * DIM / 4) return;
    float4 v = in[i];
    int c = (i * 4) & (DIM - 1);
    float4 sc = *(const float4*)&scsh[c];
    float4 sh = *(const float4*)&scsh[DIM + c];
    float4 r;
    r.x = fmaf(v.x, sc.x, sh.x);
    r.y = fmaf(v.y, sc.y, sh.y);
    r.z = fmaf(v.z, sc.z, sh.z);
    r.w = fmaf(v.w, sc.w, sh.w);
    outf[i] = r;
}

// ---------------- launch ----------------

extern "C" void kernel_launch(void* const* d_in, const int* in_sizes, int n_in,
                              void* d_out, int out_size, void* d_ws, size_t ws_size,
                              hipStream_t stream){
    const float* x   = (const float*)d_in[0];
    const int*   src = (const int*)d_in[1];
    const int*   dst = src + N_EDGES;
    const float* Ws  = (const float*)d_in[2];
    const float* bs  = (const float*)d_in[3];
    const float* gs  = (const float*)d_in[4];
    const float* be  = (const float*)d_in[5];

    char* w = (char*)d_ws;
    int*   degcnt = (int*)(w);                  // 50000 i   [0, 200000)
    float* stats  = (float*)(w + 200000);       // 1024 f (4 layers x 256)
    float* scsh   = (float*)(w + 204096);       // 1024 f (4 layers x 256)
    float* dis    = (float*)(w + 208192);       // 50000 f
    int*   rowptr = (int*)(w + 408192);         // 50001 i (pad)
    int*   wptr   = (int*)(w + 608208);         // 50000 i
    int*   esrc   = (int*)(w + 808208);         // 800000 i
    float* bufA   = (float*)(w + 4008208);      // 6.4M f  (agg out / layer in)
    unsigned short* hb = (unsigned short*)(w + 29608208);  // 6.4M bf16 (h)
    // total: 42,408,208 bytes

    k_zero<<<(51024 + 255)/256, 256, 0, stream>>>(degcnt, 51024);
    k_count<<<3125, 256, 0, stream>>>(dst, degcnt);
    k_dis<<<196, 256, 0, stream>>>(degcnt, dis);
    k_scan<<<1, 256, 0, stream>>>(degcnt, rowptr, wptr);
    k_fill<<<3125, 256, 0, stream>>>(src, dst, wptr, esrc);

    for (int L = 0; L < NLAYERS; L++){
        const float* zin = (L == 0) ? x : bufA;
        if (L == 0)
            k_gemm<false><<<1563, 256, 0, stream>>>(zin, Ws + L*DIM*DIM,
                                                    nullptr, hb);
        else
            k_gemm<true><<<1563, 256, 0, stream>>>(zin, Ws + L*DIM*DIM,
                                                   scsh + (L-1)*256, hb);
        k_agg<<<2048, 256, 0, stream>>>(hb, rowptr, esrc, dis, bs + L*DIM,
                                        bufA, stats + L*256);
        k_bnstat<<<1, 128, 0, stream>>>(stats + L*256, gs + L*DIM, be + L*DIM,
                                        scsh + L*256);
    }
    k_bn<<<6250, 256, 0, stream>>>((const float4*)bufA, scsh + 3*256,
                                   (float4*)d_out);
}

// Round 6
// 986.732 us; speedup vs baseline: 1.1404x; 1.0072x over previous
//
#include <hip/hip_runtime.h>

#define N_NODES 50000
#define N_EDGES 800000
#define DIM 128
#define NLAYERS 4
#define BN_EPS 1e-5f

__device__ __forceinline__ float bf2f(unsigned short u){
    union { unsigned int i; float f; } x; x.i = ((unsigned int)u) << 16; return x.f;
}
__device__ __forceinline__ unsigned short f2bf(float f){
    union { float f; unsigned int i; } x; x.f = f;
    unsigned int lsb = (x.i >> 16) & 1u;
    unsigned int r = x.i + 0x7fffu + lsb;
    return (unsigned short)(r >> 16);
}

// ---------------- prep kernels ----------------

__global__ __launch_bounds__(256) void k_zero(int* __restrict__ p, int n){
    int i = blockIdx.x * 256 + threadIdx.x;
    if (i < n) p[i] = 0;
}

__global__ __launch_bounds__(256) void k_count(const int* __restrict__ dst,
                                               int* __restrict__ degcnt){
    int e = blockIdx.x * 256 + threadIdx.x;
    if (e < N_EDGES) atomicAdd(&degcnt[dst[e]], 1);
}

__global__ __launch_bounds__(256) void k_dis(const int* __restrict__ degcnt,
                                             float* __restrict__ dis){
    int i = blockIdx.x * 256 + threadIdx.x;
    if (i < N_NODES) dis[i] = rsqrtf((float)degcnt[i] + 1.0f);
}

// single-block 256-thread chunked exclusive scan: degcnt -> rowptr (+wptr copy)
__global__ __launch_bounds__(256) void k_scan(const int* __restrict__ degcnt,
                                              int* __restrict__ rowptr,
                                              int* __restrict__ wptr){
    __shared__ int sums[256];
    const int CH = (N_NODES + 255) / 256;            // 196
    int t = threadIdx.x;
    int lo = t * CH;
    int hi = lo + CH; if (hi > N_NODES) hi = N_NODES;
    int s = 0;
    for (int i = lo; i < hi; i++) s += degcnt[i];
    sums[t] = s;
    __syncthreads();
    for (int off = 1; off < 256; off <<= 1){
        int v = (t >= off) ? sums[t - off] : 0;
        __syncthreads();
        sums[t] += v;
        __syncthreads();
    }
    int run = (t == 0) ? 0 : sums[t - 1];
    for (int i = lo; i < hi; i++){
        rowptr[i] = run; wptr[i] = run;
        run += degcnt[i];
    }
    if (t == 255) rowptr[N_NODES] = run;
}

// CSR fill with fused per-edge weight: epair[p] = {src, dis[src]*dis[dst]}
__global__ __launch_bounds__(256) void k_fill(const int* __restrict__ src,
                                              const int* __restrict__ dst,
                                              const float* __restrict__ dis,
                                              int* __restrict__ wptr,
                                              int2* __restrict__ epair){
    int e = blockIdx.x * 256 + threadIdx.x;
    if (e < N_EDGES){
        int s = src[e], d = dst[e];
        float w = dis[s] * dis[d];
        int p = atomicAdd(&wptr[d], 1);
        int2 pr; pr.x = s; pr.y = __float_as_int(w);
        epair[p] = pr;
    }
}

// ---------------- per-layer kernels ----------------

// h = z' @ W. MODE 0: z fp32, no BN (layer 0). MODE 1: z bf16, BN fold on load.
// W fp32 [128,128] row-major [k][c]; h stored BF16 [N,128].
// 32 rows/block, 256 threads, 4x4 micro-tile. LDS: 16KB fp32 z tile.
template<int MODE>
__global__ __launch_bounds__(256) void k_gemm(const void* __restrict__ zraw,
                                              const float* __restrict__ W,
                                              const float* __restrict__ scsh,
                                              unsigned short* __restrict__ hb){
    __shared__ float zs[32][DIM];              // 16 KB
    int tid = threadIdx.x;
    int row0 = blockIdx.x * 32;

    if (MODE == 0){
        const float4* zv = (const float4*)zraw;
        float4* zsv = (float4*)(&zs[0][0]);
        #pragma unroll
        for (int i = 0; i < 4; i++){
            int idx = tid + 256*i;             // float4 units within tile
            int r = idx >> 5;                  // 32 float4 per row
            float4 val = make_float4(0.f, 0.f, 0.f, 0.f);
            if (row0 + r < N_NODES) val = zv[row0*32 + idx];
            zsv[idx] = val;
        }
    } else {
        const uint4* zv = (const uint4*)zraw;  // 8 bf16 per uint4
        #pragma unroll
        for (int i = 0; i < 2; i++){
            int idx = tid + 256*i;             // uint4 units, 512 total
            int r = idx >> 4;                  // 16 uint4 per row
            int c = (idx & 15) * 8;
            uint4 raw = make_uint4(0,0,0,0);
            if (row0 + r < N_NODES) raw = zv[row0*16 + idx];
            float4 sc0 = *(const float4*)&scsh[c];
            float4 sc1 = *(const float4*)&scsh[c + 4];
            float4 sh0 = *(const float4*)&scsh[DIM + c];
            float4 sh1 = *(const float4*)&scsh[DIM + c + 4];
            unsigned int u[4] = {raw.x, raw.y, raw.z, raw.w};
            float v[8];
            #pragma unroll
            for (int j = 0; j < 4; j++){
                v[2*j]   = bf2f((unsigned short)(u[j] & 0xffff));
                v[2*j+1] = bf2f((unsigned short)(u[j] >> 16));
            }
            zs[r][c+0] = fmaf(v[0], sc0.x, sh0.x);
            zs[r][c+1] = fmaf(v[1], sc0.y, sh0.y);
            zs[r][c+2] = fmaf(v[2], sc0.z, sh0.z);
            zs[r][c+3] = fmaf(v[3], sc0.w, sh0.w);
            zs[r][c+4] = fmaf(v[4], sc1.x, sh1.x);
            zs[r][c+5] = fmaf(v[5], sc1.y, sh1.y);
            zs[r][c+6] = fmaf(v[6], sc1.z, sh1.z);
            zs[r][c+7] = fmaf(v[7], sc1.w, sh1.w);
        }
    }
    __syncthreads();

    int r0 = (tid >> 5) * 4;                   // 8 row groups
    int c0 = (tid & 31) * 4;                   // 32 col groups
    float acc[4][4] = {};

    for (int k = 0; k < DIM; k += 4){
        float4 a[4];
        #pragma unroll
        for (int r = 0; r < 4; r++) a[r] = *(const float4*)&zs[r0 + r][k];
        float4 wv[4];
        #pragma unroll
        for (int kk = 0; kk < 4; kk++)
            wv[kk] = *(const float4*)&W[(k + kk)*DIM + c0];
        #pragma unroll
        for (int r = 0; r < 4; r++){
            float av[4] = {a[r].x, a[r].y, a[r].z, a[r].w};
            #pragma unroll
            for (int kk = 0; kk < 4; kk++){
                acc[r][0] = fmaf(av[kk], wv[kk].x, acc[r][0]);
                acc[r][1] = fmaf(av[kk], wv[kk].y, acc[r][1]);
                acc[r][2] = fmaf(av[kk], wv[kk].z, acc[r][2]);
                acc[r][3] = fmaf(av[kk], wv[kk].w, acc[r][3]);
            }
        }
    }
    #pragma unroll
    for (int r = 0; r < 4; r++){
        int row = row0 + r0 + r;
        if (row < N_NODES){
            ushort4 o;
            o.x = f2bf(acc[r][0]); o.y = f2bf(acc[r][1]);
            o.z = f2bf(acc[r][2]); o.w = f2bf(acc[r][3]);
            *(ushort4*)&hb[row*DIM + c0] = o;
        }
    }
}

// CSR aggregation + bias + ReLU + per-column sum/sumsq partials.
// h bf16; one wave per node, lane holds cols (2*lane, 2*lane+1).
// Per edge: 1 streamed int2 {src,w} + 1 random 256B h-row gather.
__global__ __launch_bounds__(256) void k_agg(const unsigned short* __restrict__ h,
                                             const int* __restrict__ rowptr,
                                             const int2* __restrict__ epair,
                                             const float* __restrict__ dis,
                                             const float* __restrict__ bias,
                                             unsigned short* __restrict__ out,
                                             float* __restrict__ stats){
    int lane = threadIdx.x & 63;
    int w    = threadIdx.x >> 6;
    const ushort2* h2 = (const ushort2*)h;
    ushort2* o2 = (ushort2*)out;
    float b0 = bias[2*lane], b1 = bias[2*lane + 1];
    float s0 = 0.f, s1 = 0.f, q0 = 0.f, q1 = 0.f;

    for (int node = blockIdx.x*4 + w; node < N_NODES; node += gridDim.x*4){
        float di = dis[node];
        int e0 = rowptr[node], e1 = rowptr[node + 1];
        ushort2 hv = h2[node*64 + lane];
        float dii = di * di;
        float p0[4] = {bf2f(hv.x) * dii, 0.f, 0.f, 0.f};
        float p1[4] = {bf2f(hv.y) * dii, 0.f, 0.f, 0.f};

        int e = e0;
        for (; e + 8 <= e1; e += 8){
            int2 pr[8];
            #pragma unroll
            for (int j = 0; j < 8; j++) pr[j] = epair[e + j];
            ushort2 xs[8];
            #pragma unroll
            for (int j = 0; j < 8; j++) xs[j] = h2[pr[j].x*64 + lane];
            #pragma unroll
            for (int j = 0; j < 8; j++){
                float we = __int_as_float(pr[j].y);
                p0[j & 3] = fmaf(bf2f(xs[j].x), we, p0[j & 3]);
                p1[j & 3] = fmaf(bf2f(xs[j].y), we, p1[j & 3]);
            }
        }
        for (; e < e1; e++){
            int2 pr = epair[e];
            float we = __int_as_float(pr.y);
            ushort2 xv = h2[pr.x*64 + lane];
            p0[0] = fmaf(bf2f(xv.x), we, p0[0]);
            p1[0] = fmaf(bf2f(xv.y), we, p1[0]);
        }
        float a0 = (p0[0] + p0[1]) + (p0[2] + p0[3]) + b0;
        float a1 = (p1[0] + p1[1]) + (p1[2] + p1[3]) + b1;
        a0 = fmaxf(a0, 0.f); a1 = fmaxf(a1, 0.f);
        ushort2 ov; ov.x = f2bf(a0); ov.y = f2bf(a1);
        o2[node*64 + lane] = ov;
        s0 += a0; s1 += a1; q0 += a0*a0; q1 += a1*a1;
    }

    __shared__ float red[4][64][4];
    red[w][lane][0] = s0; red[w][lane][1] = s1;
    red[w][lane][2] = q0; red[w][lane][3] = q1;
    __syncthreads();
    if (w == 0){
        #pragma unroll
        for (int ww = 1; ww < 4; ww++){
            s0 += red[ww][lane][0]; s1 += red[ww][lane][1];
            q0 += red[ww][lane][2]; q1 += red[ww][lane][3];
        }
        atomicAdd(&stats[2*lane],       s0);
        atomicAdd(&stats[2*lane + 1],   s1);
        atomicAdd(&stats[DIM + 2*lane],     q0);
        atomicAdd(&stats[DIM + 2*lane + 1], q1);
    }
}

// stats -> per-column scale/shift:  sc = rstd*gamma, sh = beta - mu*sc
__global__ void k_bnstat(const float* __restrict__ stats,
                         const float* __restrict__ gamma,
                         const float* __restrict__ beta,
                         float* __restrict__ scsh){
    int c = threadIdx.x;
    float mu  = stats[c] * (1.0f / N_NODES);
    float var = stats[DIM + c] * (1.0f / N_NODES) - mu * mu;
    float sc  = rsqrtf(var + BN_EPS) * gamma[c];
    scsh[c] = sc;
    scsh[DIM + c] = beta[c] - mu * sc;
}

// final-layer BN apply: bf16 in -> fp32 out = a*sc + sh
__global__ __launch_bounds__(256) void k_bn(const uint4* __restrict__ in,
                                            const float* __restrict__ scsh,
                                            float4* __restrict__ outf){
    int i = blockIdx.x * 256 + threadIdx.x;         // uint4 (8 bf16) index
    if (i >= N_NODES * DIM / 8) return;
    uint4 raw = in[i];
    int c = (i * 8) & (DIM - 1);
    float4 sc0 = *(const float4*)&scsh[c];
    float4 sc1 = *(const float4*)&scsh[c + 4];
    float4 sh0 = *(const float4*)&scsh[DIM + c];
    float4 sh1 = *(const float4*)&scsh[DIM + c + 4];
    unsigned int u[4] = {raw.x, raw.y, raw.z, raw.w};
    float v[8];
    #pragma unroll
    for (int j = 0; j < 4; j++){
        v[2*j]   = bf2f((unsigned short)(u[j] & 0xffff));
        v[2*j+1] = bf2f((unsigned short)(u[j] >> 16));
    }
    float4 r0, r1;
    r0.x = fmaf(v[0], sc0.x, sh0.x);
    r0.y = fmaf(v[1], sc0.y, sh0.y);
    r0.z = fmaf(v[2], sc0.z, sh0.z);
    r0.w = fmaf(v[3], sc0.w, sh0.w);
    r1.x = fmaf(v[4], sc1.x, sh1.x);
    r1.y = fmaf(v[5], sc1.y, sh1.y);
    r1.z = fmaf(v[6], sc1.z, sh1.z);
    r1.w = fmaf(v[7], sc1.w, sh1.w);
    outf[2*i]   = r0;
    outf[2*i+1] = r1;
}

// ---------------- launch ----------------

extern "C" void kernel_launch(void* const* d_in, const int* in_sizes, int n_in,
                              void* d_out, int out_size, void* d_ws, size_t ws_size,
                              hipStream_t stream){
    const float* x   = (const float*)d_in[0];
    const int*   src = (const int*)d_in[1];
    const int*   dst = src + N_EDGES;
    const float* Ws  = (const float*)d_in[2];
    const float* bs  = (const float*)d_in[3];
    const float* gs  = (const float*)d_in[4];
    const float* be  = (const float*)d_in[5];

    char* w = (char*)d_ws;
    int*   degcnt = (int*)(w);                         // 50000 i  [0,200000)
    float* stats  = (float*)(w + 200000);              // 1024 f
    float* scsh   = (float*)(w + 204096);              // 1024 f
    float* dis    = (float*)(w + 208192);              // 50000 f
    int*   rowptr = (int*)(w + 408192);                // 50001 i (pad)
    int*   wptr   = (int*)(w + 608208);                // 50000 i
    int2*  epair  = (int2*)(w + 808208);               // 800000 int2 (6.4MB)
    unsigned short* bufA = (unsigned short*)(w + 7208208);   // 6.4M bf16 (12.8MB)
    unsigned short* hb   = (unsigned short*)(w + 20008208);  // 6.4M bf16 (12.8MB)
    // total: 32,808,208 bytes

    k_zero<<<(51024 + 255)/256, 256, 0, stream>>>(degcnt, 51024);
    k_count<<<3125, 256, 0, stream>>>(dst, degcnt);
    k_dis<<<196, 256, 0, stream>>>(degcnt, dis);
    k_scan<<<1, 256, 0, stream>>>(degcnt, rowptr, wptr);
    k_fill<<<3125, 256, 0, stream>>>(src, dst, dis, wptr, epair);

    for (int L = 0; L < NLAYERS; L++){
        if (L == 0)
            k_gemm<0><<<1563, 256, 0, stream>>>(x, Ws + L*DIM*DIM,
                                                nullptr, hb);
        else
            k_gemm<1><<<1563, 256, 0, stream>>>(bufA, Ws + L*DIM*DIM,
                                                scsh + (L-1)*256, hb);
        k_agg<<<2048, 256, 0, stream>>>(hb, rowptr, epair, dis, bs + L*DIM,
                                        bufA, stats + L*256);
        k_bnstat<<<1, 128, 0, stream>>>(stats + L*256, gs + L*DIM, be + L*DIM,
                                        scsh + L*256);
    }
    k_bn<<<3125, 256, 0, stream>>>((const uint4*)bufA, scsh + 3*256,
                                   (float4*)d_out);
}

// Round 7
// 763.806 us; speedup vs baseline: 1.4733x; 1.2919x over previous
//
#include <hip/hip_runtime.h>

#define N_NODES 50000
#define N_EDGES 800000
#define DIM 128
#define NLAYERS 4
#define BN_EPS 1e-5f

__device__ __forceinline__ float bf2f(unsigned short u){
    union { unsigned int i; float f; } x; x.i = ((unsigned int)u) << 16; return x.f;
}
__device__ __forceinline__ unsigned short f2bf(float f){
    union { float f; unsigned int i; } x; x.f = f;
    unsigned int lsb = (x.i >> 16) & 1u;
    unsigned int r = x.i + 0x7fffu + lsb;
    return (unsigned short)(r >> 16);
}

// ---------------- prep kernels ----------------

__global__ __launch_bounds__(256) void k_zero(int* __restrict__ p, int n){
    int i = blockIdx.x * 256 + threadIdx.x;
    if (i < n) p[i] = 0;
}

__global__ __launch_bounds__(256) void k_count(const int* __restrict__ dst,
                                               int* __restrict__ degcnt){
    int e = blockIdx.x * 256 + threadIdx.x;
    if (e < N_EDGES) atomicAdd(&degcnt[dst[e]], 1);
}

__global__ __launch_bounds__(256) void k_dis(const int* __restrict__ degcnt,
                                             float* __restrict__ dis){
    int i = blockIdx.x * 256 + threadIdx.x;
    if (i < N_NODES) dis[i] = rsqrtf((float)degcnt[i] + 1.0f);
}

// single-block 256-thread chunked exclusive scan: degcnt -> rowptr (+wptr copy)
__global__ __launch_bounds__(256) void k_scan(const int* __restrict__ degcnt,
                                              int* __restrict__ rowptr,
                                              int* __restrict__ wptr){
    __shared__ int sums[256];
    const int CH = (N_NODES + 255) / 256;            // 196
    int t = threadIdx.x;
    int lo = t * CH;
    int hi = lo + CH; if (hi > N_NODES) hi = N_NODES;
    int s = 0;
    for (int i = lo; i < hi; i++) s += degcnt[i];
    sums[t] = s;
    __syncthreads();
    for (int off = 1; off < 256; off <<= 1){
        int v = (t >= off) ? sums[t - off] : 0;
        __syncthreads();
        sums[t] += v;
        __syncthreads();
    }
    int run = (t == 0) ? 0 : sums[t - 1];
    for (int i = lo; i < hi; i++){
        rowptr[i] = run; wptr[i] = run;
        run += degcnt[i];
    }
    if (t == 255) rowptr[N_NODES] = run;
}

// CSR fill with fused per-edge weight: epair[p] = {src, dis[src]*dis[dst]}
__global__ __launch_bounds__(256) void k_fill(const int* __restrict__ src,
                                              const int* __restrict__ dst,
                                              const float* __restrict__ dis,
                                              int* __restrict__ wptr,
                                              int2* __restrict__ epair){
    int e = blockIdx.x * 256 + threadIdx.x;
    if (e < N_EDGES){
        int s = src[e], d = dst[e];
        float w = dis[s] * dis[d];
        int p = atomicAdd(&wptr[d], 1);
        int2 pr; pr.x = s; pr.y = __float_as_int(w);
        epair[p] = pr;
    }
}

// ---------------- per-layer kernels ----------------
// Grouped feature layout: t[g][node][32 cols], g = col>>5. Each group slice is
// 50000*64B = 3.2MB -> fits one XCD's 4MB L2 when only that XCD touches it.

// h = z' @ W. MODE 0: z fp32 std layout, no BN. MODE 1: z bf16 grouped, BN fold.
// W fp32 [128,128] row-major [k][c]; h written BF16 grouped layout.
template<int MODE>
__global__ __launch_bounds__(256) void k_gemm(const void* __restrict__ zraw,
                                              const float* __restrict__ W,
                                              const float* __restrict__ scsh,
                                              unsigned short* __restrict__ hb){
    __shared__ float zs[32][DIM];              // 16 KB
    int tid = threadIdx.x;
    int row0 = blockIdx.x * 32;

    if (MODE == 0){
        const float4* zv = (const float4*)zraw;
        float4* zsv = (float4*)(&zs[0][0]);
        #pragma unroll
        for (int i = 0; i < 4; i++){
            int idx = tid + 256*i;             // float4 units within tile
            int r = idx >> 5;                  // 32 float4 per row
            float4 val = make_float4(0.f, 0.f, 0.f, 0.f);
            if (row0 + r < N_NODES) val = zv[row0*32 + idx];
            zsv[idx] = val;
        }
    } else {
        const uint4* zv = (const uint4*)zraw;  // grouped: g*(N*4) + row*4 + wi/8
        #pragma unroll
        for (int i = 0; i < 2; i++){
            int idx = tid + 256*i;             // 512 uint4 units
            int r = idx >> 4;                  // 16 uint4 per row
            int c = (idx & 15) * 8;
            int gg = c >> 5, wi = c & 31;
            uint4 raw = make_uint4(0,0,0,0);
            int row = row0 + r;
            if (row < N_NODES) raw = zv[gg*(N_NODES*4) + row*4 + (wi >> 3)];
            float4 sc0 = *(const float4*)&scsh[c];
            float4 sc1 = *(const float4*)&scsh[c + 4];
            float4 sh0 = *(const float4*)&scsh[DIM + c];
            float4 sh1 = *(const float4*)&scsh[DIM + c + 4];
            unsigned int u[4] = {raw.x, raw.y, raw.z, raw.w};
            float v[8];
            #pragma unroll
            for (int j = 0; j < 4; j++){
                v[2*j]   = bf2f((unsigned short)(u[j] & 0xffff));
                v[2*j+1] = bf2f((unsigned short)(u[j] >> 16));
            }
            zs[r][c+0] = fmaf(v[0], sc0.x, sh0.x);
            zs[r][c+1] = fmaf(v[1], sc0.y, sh0.y);
            zs[r][c+2] = fmaf(v[2], sc0.z, sh0.z);
            zs[r][c+3] = fmaf(v[3], sc0.w, sh0.w);
            zs[r][c+4] = fmaf(v[4], sc1.x, sh1.x);
            zs[r][c+5] = fmaf(v[5], sc1.y, sh1.y);
            zs[r][c+6] = fmaf(v[6], sc1.z, sh1.z);
            zs[r][c+7] = fmaf(v[7], sc1.w, sh1.w);
        }
    }
    __syncthreads();

    int r0 = (tid >> 5) * 4;                   // 8 row groups
    int c0 = (tid & 31) * 4;                   // 32 col groups
    float acc[4][4] = {};

    for (int k = 0; k < DIM; k += 4){
        float4 a[4];
        #pragma unroll
        for (int r = 0; r < 4; r++) a[r] = *(const float4*)&zs[r0 + r][k];
        float4 wv[4];
        #pragma unroll
        for (int kk = 0; kk < 4; kk++)
            wv[kk] = *(const float4*)&W[(k + kk)*DIM + c0];
        #pragma unroll
        for (int r = 0; r < 4; r++){
            float av[4] = {a[r].x, a[r].y, a[r].z, a[r].w};
            #pragma unroll
            for (int kk = 0; kk < 4; kk++){
                acc[r][0] = fmaf(av[kk], wv[kk].x, acc[r][0]);
                acc[r][1] = fmaf(av[kk], wv[kk].y, acc[r][1]);
                acc[r][2] = fmaf(av[kk], wv[kk].z, acc[r][2]);
                acc[r][3] = fmaf(av[kk], wv[kk].w, acc[r][3]);
            }
        }
    }
    int gg = c0 >> 5, wi = c0 & 31;
    #pragma unroll
    for (int r = 0; r < 4; r++){
        int row = row0 + r0 + r;
        if (row < N_NODES){
            ushort4 o;
            o.x = f2bf(acc[r][0]); o.y = f2bf(acc[r][1]);
            o.z = f2bf(acc[r][2]); o.w = f2bf(acc[r][3]);
            *(ushort4*)&hb[(size_t)gg*N_NODES*32 + (size_t)row*32 + wi] = o;
        }
    }
}

// CSR aggregation + bias + ReLU + per-column stats, feature-group partitioned.
// group = blockIdx&3 (XCD-stable under %8 round-robin dispatch). Wave layout:
// 16 lanes per edge (ushort2 cols), 4 edges per load, x2 unrolled.
__global__ __launch_bounds__(256) void k_agg(const unsigned short* __restrict__ h,
                                             const int* __restrict__ rowptr,
                                             const int2* __restrict__ epair,
                                             const float* __restrict__ dis,
                                             const float* __restrict__ bias,
                                             unsigned short* __restrict__ out,
                                             float* __restrict__ stats){
    int lane = threadIdx.x & 63;
    int w    = threadIdx.x >> 6;
    int g    = blockIdx.x & 3;
    int sub  = lane >> 4;                      // which edge of 4
    int cp   = lane & 15;                      // col pair within group
    const ushort2* hg = (const ushort2*)(h + (size_t)g * N_NODES * 32);
    ushort2* og = (ushort2*)(out + (size_t)g * N_NODES * 32);
    float b0 = bias[g*32 + 2*cp], b1 = bias[g*32 + 2*cp + 1];
    float s0 = 0.f, s1 = 0.f, q0 = 0.f, q1 = 0.f;
    int bg = blockIdx.x >> 2;                  // block index within group
    int nstride = (gridDim.x >> 2) * 4;

    for (int node = bg*4 + w; node < N_NODES; node += nstride){
        float di = dis[node];
        int e0 = rowptr[node], e1 = rowptr[node + 1];
        float pa0 = 0.f, pa1 = 0.f, pb0 = 0.f, pb1 = 0.f;
        if (sub == 0){
            ushort2 hv = hg[node*16 + cp];
            float dii = di * di;
            pa0 = bf2f(hv.x) * dii; pa1 = bf2f(hv.y) * dii;
        }
        int e = e0;
        for (; e + 8 <= e1; e += 8){
            int2 pra = epair[e + sub];
            int2 prb = epair[e + 4 + sub];
            ushort2 xa = hg[pra.x*16 + cp];
            ushort2 xb = hg[prb.x*16 + cp];
            float wa = __int_as_float(pra.y);
            float wb = __int_as_float(prb.y);
            pa0 = fmaf(bf2f(xa.x), wa, pa0);
            pa1 = fmaf(bf2f(xa.y), wa, pa1);
            pb0 = fmaf(bf2f(xb.x), wb, pb0);
            pb1 = fmaf(bf2f(xb.y), wb, pb1);
        }
        for (; e < e1; e += 4){
            int ide = e + sub;
            int2 pr = (ide < e1) ? epair[ide] : make_int2(0, 0);
            ushort2 xv = hg[pr.x*16 + cp];
            float we = __int_as_float(pr.y);   // 0.0f for masked lanes
            pa0 = fmaf(bf2f(xv.x), we, pa0);
            pa1 = fmaf(bf2f(xv.y), we, pa1);
        }
        float r0 = pa0 + pb0, r1 = pa1 + pb1;
        r0 += __shfl_xor(r0, 16); r1 += __shfl_xor(r1, 16);
        r0 += __shfl_xor(r0, 32); r1 += __shfl_xor(r1, 32);
        if (sub == 0){
            float a0 = fmaxf(r0 + b0, 0.f);
            float a1 = fmaxf(r1 + b1, 0.f);
            ushort2 ov; ov.x = f2bf(a0); ov.y = f2bf(a1);
            og[node*16 + cp] = ov;
            s0 += a0; s1 += a1; q0 += a0*a0; q1 += a1*a1;
        }
    }

    __shared__ float red[4][16][4];
    if (sub == 0){
        red[w][cp][0] = s0; red[w][cp][1] = s1;
        red[w][cp][2] = q0; red[w][cp][3] = q1;
    }
    __syncthreads();
    if (w == 0 && sub == 0){
        #pragma unroll
        for (int ww = 1; ww < 4; ww++){
            s0 += red[ww][cp][0]; s1 += red[ww][cp][1];
            q0 += red[ww][cp][2]; q1 += red[ww][cp][3];
        }
        int c = g*32 + 2*cp;
        atomicAdd(&stats[c],         s0);
        atomicAdd(&stats[c + 1],     s1);
        atomicAdd(&stats[DIM + c],     q0);
        atomicAdd(&stats[DIM + c + 1], q1);
    }
}

// stats -> per-column scale/shift:  sc = rstd*gamma, sh = beta - mu*sc
__global__ void k_bnstat(const float* __restrict__ stats,
                         const float* __restrict__ gamma,
                         const float* __restrict__ beta,
                         float* __restrict__ scsh){
    int c = threadIdx.x;
    float mu  = stats[c] * (1.0f / N_NODES);
    float var = stats[DIM + c] * (1.0f / N_NODES) - mu * mu;
    float sc  = rsqrtf(var + BN_EPS) * gamma[c];
    scsh[c] = sc;
    scsh[DIM + c] = beta[c] - mu * sc;
}

// final-layer BN apply: grouped bf16 in -> standard-layout fp32 out
__global__ __launch_bounds__(256) void k_bn(const uint4* __restrict__ in,
                                            const float* __restrict__ scsh,
                                            float4* __restrict__ outf){
    int i = blockIdx.x * 256 + threadIdx.x;         // 8-bf16 chunk index
    if (i >= N_NODES * DIM / 8) return;
    int row = i >> 4;
    int c = (i * 8) & (DIM - 1);
    int gg = c >> 5, wi = c & 31;
    uint4 raw = in[gg*(N_NODES*4) + row*4 + (wi >> 3)];
    float4 sc0 = *(const float4*)&scsh[c];
    float4 sc1 = *(const float4*)&scsh[c + 4];
    float4 sh0 = *(const float4*)&scsh[DIM + c];
    float4 sh1 = *(const float4*)&scsh[DIM + c + 4];
    unsigned int u[4] = {raw.x, raw.y, raw.z, raw.w};
    float v[8];
    #pragma unroll
    for (int j = 0; j < 4; j++){
        v[2*j]   = bf2f((unsigned short)(u[j] & 0xffff));
        v[2*j+1] = bf2f((unsigned short)(u[j] >> 16));
    }
    float4 r0, r1;
    r0.x = fmaf(v[0], sc0.x, sh0.x);
    r0.y = fmaf(v[1], sc0.y, sh0.y);
    r0.z = fmaf(v[2], sc0.z, sh0.z);
    r0.w = fmaf(v[3], sc0.w, sh0.w);
    r1.x = fmaf(v[4], sc1.x, sh1.x);
    r1.y = fmaf(v[5], sc1.y, sh1.y);
    r1.z = fmaf(v[6], sc1.z, sh1.z);
    r1.w = fmaf(v[7], sc1.w, sh1.w);
    outf[2*i]   = r0;
    outf[2*i+1] = r1;
}

// ---------------- launch ----------------

extern "C" void kernel_launch(void* const* d_in, const int* in_sizes, int n_in,
                              void* d_out, int out_size, void* d_ws, size_t ws_size,
                              hipStream_t stream){
    const float* x   = (const float*)d_in[0];
    const int*   src = (const int*)d_in[1];
    const int*   dst = src + N_EDGES;
    const float* Ws  = (const float*)d_in[2];
    const float* bs  = (const float*)d_in[3];
    const float* gs  = (const float*)d_in[4];
    const float* be  = (const float*)d_in[5];

    char* w = (char*)d_ws;
    int*   degcnt = (int*)(w);                         // 50000 i  [0,200000)
    float* stats  = (float*)(w + 200000);              // 1024 f
    float* scsh   = (float*)(w + 204096);              // 1024 f
    float* dis    = (float*)(w + 208192);              // 50000 f
    int*   rowptr = (int*)(w + 408192);                // 50001 i (pad)
    int*   wptr   = (int*)(w + 608208);                // 50000 i
    int2*  epair  = (int2*)(w + 808208);               // 800000 int2 (6.4MB)
    unsigned short* bufA = (unsigned short*)(w + 7208208);   // grouped bf16 (12.8MB)
    unsigned short* hb   = (unsigned short*)(w + 20008208);  // grouped bf16 (12.8MB)
    // total: 32,808,208 bytes

    k_zero<<<(51024 + 255)/256, 256, 0, stream>>>(degcnt, 51024);
    k_count<<<3125, 256, 0, stream>>>(dst, degcnt);
    k_dis<<<196, 256, 0, stream>>>(degcnt, dis);
    k_scan<<<1, 256, 0, stream>>>(degcnt, rowptr, wptr);
    k_fill<<<3125, 256, 0, stream>>>(src, dst, dis, wptr, epair);

    for (int L = 0; L < NLAYERS; L++){
        if (L == 0)
            k_gemm<0><<<1563, 256, 0, stream>>>(x, Ws + L*DIM*DIM,
                                                nullptr, hb);
        else
            k_gemm<1><<<1563, 256, 0, stream>>>(bufA, Ws + L*DIM*DIM,
                                                scsh + (L-1)*256, hb);
        k_agg<<<2048, 256, 0, stream>>>(hb, rowptr, epair, dis, bs + L*DIM,
                                        bufA, stats + L*256);
        k_bnstat<<<1, 128, 0, stream>>>(stats + L*256, gs + L*DIM, be + L*DIM,
                                        scsh + L*256);
    }
    k_bn<<<3125, 256, 0, stream>>>((const uint4*)bufA, scsh + 3*256,
                                   (float4*)d_out);
}

// Round 8
// 658.450 us; speedup vs baseline: 1.7090x; 1.1600x over previous
//
#include <hip/hip_runtime.h>

#define N_NODES 50000
#define N_EDGES 800000
#define DIM 128
#define NLAYERS 4
#define BN_EPS 1e-5f
#define SCAN_BLOCKS 196   // ceil(N_NODES/256)

__device__ __forceinline__ float bf2f(unsigned short u){
    union { unsigned int i; float f; } x; x.i = ((unsigned int)u) << 16; return x.f;
}
__device__ __forceinline__ unsigned short f2bf(float f){
    union { float f; unsigned int i; } x; x.f = f;
    unsigned int lsb = (x.i >> 16) & 1u;
    unsigned int r = x.i + 0x7fffu + lsb;
    return (unsigned short)(r >> 16);
}

// ---------------- prep kernels ----------------

__global__ __launch_bounds__(256) void k_zero(int* __restrict__ p, int n){
    int i = blockIdx.x * 256 + threadIdx.x;
    if (i < n) p[i] = 0;
}

__global__ __launch_bounds__(256) void k_count(const int* __restrict__ dst,
                                               int* __restrict__ degcnt){
    int e = blockIdx.x * 256 + threadIdx.x;
    if (e < N_EDGES) atomicAdd(&degcnt[dst[e]], 1);
}

__global__ __launch_bounds__(256) void k_dis(const int* __restrict__ degcnt,
                                             float* __restrict__ dis){
    int i = blockIdx.x * 256 + threadIdx.x;
    if (i < N_NODES) dis[i] = rsqrtf((float)degcnt[i] + 1.0f);
}

// scan phase 1: per-block exclusive scan of degcnt -> rowptr, block sums -> bsum
__global__ __launch_bounds__(256) void k_scan1(const int* __restrict__ degcnt,
                                               int* __restrict__ rowptr,
                                               int* __restrict__ bsum){
    __shared__ int tmp[256];
    int t = threadIdx.x;
    int i = blockIdx.x * 256 + t;
    int v = (i < N_NODES) ? degcnt[i] : 0;
    tmp[t] = v;
    __syncthreads();
    #pragma unroll
    for (int off = 1; off < 256; off <<= 1){
        int u = (t >= off) ? tmp[t - off] : 0;
        __syncthreads();
        tmp[t] += u;
        __syncthreads();
    }
    if (i < N_NODES) rowptr[i] = tmp[t] - v;        // exclusive within block
    if (t == 255) bsum[blockIdx.x] = tmp[255];
}

// scan phase 2: single block exclusive scan of the 196 block sums (in place)
__global__ __launch_bounds__(256) void k_scan2(int* __restrict__ bsum){
    __shared__ int tmp[256];
    int t = threadIdx.x;
    int v = (t < SCAN_BLOCKS) ? bsum[t] : 0;
    tmp[t] = v;
    __syncthreads();
    #pragma unroll
    for (int off = 1; off < 256; off <<= 1){
        int u = (t >= off) ? tmp[t - off] : 0;
        __syncthreads();
        tmp[t] += u;
        __syncthreads();
    }
    if (t < SCAN_BLOCKS) bsum[t] = tmp[t] - v;      // exclusive
}

// scan phase 3: add block offsets; mirror to wptr; set rowptr[N]
__global__ __launch_bounds__(256) void k_scan3(const int* __restrict__ bsum,
                                               int* __restrict__ rowptr,
                                               int* __restrict__ wptr){
    int i = blockIdx.x * 256 + threadIdx.x;
    if (i < N_NODES){
        int r = rowptr[i] + bsum[blockIdx.x];
        rowptr[i] = r; wptr[i] = r;
    }
    if (i == 0) rowptr[N_NODES] = N_EDGES;
}

// CSR fill with fused per-edge weight: epair[p] = {src, dis[src]*dis[dst]}
__global__ __launch_bounds__(256) void k_fill(const int* __restrict__ src,
                                              const int* __restrict__ dst,
                                              const float* __restrict__ dis,
                                              int* __restrict__ wptr,
                                              int2* __restrict__ epair){
    int e = blockIdx.x * 256 + threadIdx.x;
    if (e < N_EDGES){
        int s = src[e], d = dst[e];
        float w = dis[s] * dis[d];
        int p = atomicAdd(&wptr[d], 1);
        int2 pr; pr.x = s; pr.y = __float_as_int(w);
        epair[p] = pr;
    }
}

// ---------------- per-layer kernels ----------------
// Grouped feature layout: t[g][node][32 cols], g = col>>5. Each group slice is
// 50000*64B = 3.2MB -> fits one XCD's 4MB L2 when only that XCD touches it.

// h = z' @ W. MODE 0: z fp32 std layout, no BN. MODE 1: z bf16 grouped, BN fold.
// W fp32 [128,128] row-major [k][c]; h written BF16 grouped layout.
template<int MODE>
__global__ __launch_bounds__(256) void k_gemm(const void* __restrict__ zraw,
                                              const float* __restrict__ W,
                                              const float* __restrict__ scsh,
                                              unsigned short* __restrict__ hb){
    __shared__ float zs[32][DIM];              // 16 KB
    int tid = threadIdx.x;
    int row0 = blockIdx.x * 32;

    if (MODE == 0){
        const float4* zv = (const float4*)zraw;
        float4* zsv = (float4*)(&zs[0][0]);
        #pragma unroll
        for (int i = 0; i < 4; i++){
            int idx = tid + 256*i;             // float4 units within tile
            int r = idx >> 5;                  // 32 float4 per row
            float4 val = make_float4(0.f, 0.f, 0.f, 0.f);
            if (row0 + r < N_NODES) val = zv[row0*32 + idx];
            zsv[idx] = val;
        }
    } else {
        const uint4* zv = (const uint4*)zraw;  // grouped: g*(N*4) + row*4 + wi/8
        #pragma unroll
        for (int i = 0; i < 2; i++){
            int idx = tid + 256*i;             // 512 uint4 units
            int r = idx >> 4;                  // 16 uint4 per row
            int c = (idx & 15) * 8;
            int gg = c >> 5, wi = c & 31;
            uint4 raw = make_uint4(0,0,0,0);
            int row = row0 + r;
            if (row < N_NODES) raw = zv[gg*(N_NODES*4) + row*4 + (wi >> 3)];
            float4 sc0 = *(const float4*)&scsh[c];
            float4 sc1 = *(const float4*)&scsh[c + 4];
            float4 sh0 = *(const float4*)&scsh[DIM + c];
            float4 sh1 = *(const float4*)&scsh[DIM + c + 4];
            unsigned int u[4] = {raw.x, raw.y, raw.z, raw.w};
            float v[8];
            #pragma unroll
            for (int j = 0; j < 4; j++){
                v[2*j]   = bf2f((unsigned short)(u[j] & 0xffff));
                v[2*j+1] = bf2f((unsigned short)(u[j] >> 16));
            }
            zs[r][c+0] = fmaf(v[0], sc0.x, sh0.x);
            zs[r][c+1] = fmaf(v[1], sc0.y, sh0.y);
            zs[r][c+2] = fmaf(v[2], sc0.z, sh0.z);
            zs[r][c+3] = fmaf(v[3], sc0.w, sh0.w);
            zs[r][c+4] = fmaf(v[4], sc1.x, sh1.x);
            zs[r][c+5] = fmaf(v[5], sc1.y, sh1.y);
            zs[r][c+6] = fmaf(v[6], sc1.z, sh1.z);
            zs[r][c+7] = fmaf(v[7], sc1.w, sh1.w);
        }
    }
    __syncthreads();

    int r0 = (tid >> 5) * 4;                   // 8 row groups
    int c0 = (tid & 31) * 4;                   // 32 col groups
    float acc[4][4] = {};

    for (int k = 0; k < DIM; k += 4){
        float4 a[4];
        #pragma unroll
        for (int r = 0; r < 4; r++) a[r] = *(const float4*)&zs[r0 + r][k];
        float4 wv[4];
        #pragma unroll
        for (int kk = 0; kk < 4; kk++)
            wv[kk] = *(const float4*)&W[(k + kk)*DIM + c0];
        #pragma unroll
        for (int r = 0; r < 4; r++){
            float av[4] = {a[r].x, a[r].y, a[r].z, a[r].w};
            #pragma unroll
            for (int kk = 0; kk < 4; kk++){
                acc[r][0] = fmaf(av[kk], wv[kk].x, acc[r][0]);
                acc[r][1] = fmaf(av[kk], wv[kk].y, acc[r][1]);
                acc[r][2] = fmaf(av[kk], wv[kk].z, acc[r][2]);
                acc[r][3] = fmaf(av[kk], wv[kk].w, acc[r][3]);
            }
        }
    }
    int gg = c0 >> 5, wi = c0 & 31;
    #pragma unroll
    for (int r = 0; r < 4; r++){
        int row = row0 + r0 + r;
        if (row < N_NODES){
            ushort4 o;
            o.x = f2bf(acc[r][0]); o.y = f2bf(acc[r][1]);
            o.z = f2bf(acc[r][2]); o.w = f2bf(acc[r][3]);
            *(ushort4*)&hb[(size_t)gg*N_NODES*32 + (size_t)row*32 + wi] = o;
        }
    }
}

// CSR aggregation + bias + ReLU + per-column stats, feature-group partitioned.
// group = blockIdx&3 (XCD-stable under %8 round-robin dispatch). Wave layout:
// 16 lanes per edge (ushort2 cols), 4 edges per load, x2 unrolled.
__global__ __launch_bounds__(256) void k_agg(const unsigned short* __restrict__ h,
                                             const int* __restrict__ rowptr,
                                             const int2* __restrict__ epair,
                                             const float* __restrict__ dis,
                                             const float* __restrict__ bias,
                                             unsigned short* __restrict__ out,
                                             float* __restrict__ stats){
    int lane = threadIdx.x & 63;
    int w    = threadIdx.x >> 6;
    int g    = blockIdx.x & 3;
    int sub  = lane >> 4;                      // which edge of 4
    int cp   = lane & 15;                      // col pair within group
    const ushort2* hg = (const ushort2*)(h + (size_t)g * N_NODES * 32);
    ushort2* og = (ushort2*)(out + (size_t)g * N_NODES * 32);
    float b0 = bias[g*32 + 2*cp], b1 = bias[g*32 + 2*cp + 1];
    float s0 = 0.f, s1 = 0.f, q0 = 0.f, q1 = 0.f;
    int bg = blockIdx.x >> 2;                  // block index within group
    int nstride = (gridDim.x >> 2) * 4;

    for (int node = bg*4 + w; node < N_NODES; node += nstride){
        float di = dis[node];
        int e0 = rowptr[node], e1 = rowptr[node + 1];
        float pa0 = 0.f, pa1 = 0.f, pb0 = 0.f, pb1 = 0.f;
        if (sub == 0){
            ushort2 hv = hg[node*16 + cp];
            float dii = di * di;
            pa0 = bf2f(hv.x) * dii; pa1 = bf2f(hv.y) * dii;
        }
        int e = e0;
        for (; e + 8 <= e1; e += 8){
            int2 pra = epair[e + sub];
            int2 prb = epair[e + 4 + sub];
            ushort2 xa = hg[pra.x*16 + cp];
            ushort2 xb = hg[prb.x*16 + cp];
            float wa = __int_as_float(pra.y);
            float wb = __int_as_float(prb.y);
            pa0 = fmaf(bf2f(xa.x), wa, pa0);
            pa1 = fmaf(bf2f(xa.y), wa, pa1);
            pb0 = fmaf(bf2f(xb.x), wb, pb0);
            pb1 = fmaf(bf2f(xb.y), wb, pb1);
        }
        for (; e < e1; e += 4){
            int ide = e + sub;
            int2 pr = (ide < e1) ? epair[ide] : make_int2(0, 0);
            ushort2 xv = hg[pr.x*16 + cp];
            float we = __int_as_float(pr.y);   // 0.0f for masked lanes
            pa0 = fmaf(bf2f(xv.x), we, pa0);
            pa1 = fmaf(bf2f(xv.y), we, pa1);
        }
        float r0 = pa0 + pb0, r1 = pa1 + pb1;
        r0 += __shfl_xor(r0, 16); r1 += __shfl_xor(r1, 16);
        r0 += __shfl_xor(r0, 32); r1 += __shfl_xor(r1, 32);
        if (sub == 0){
            float a0 = fmaxf(r0 + b0, 0.f);
            float a1 = fmaxf(r1 + b1, 0.f);
            ushort2 ov; ov.x = f2bf(a0); ov.y = f2bf(a1);
            og[node*16 + cp] = ov;
            s0 += a0; s1 += a1; q0 += a0*a0; q1 += a1*a1;
        }
    }

    __shared__ float red[4][16][4];
    if (sub == 0){
        red[w][cp][0] = s0; red[w][cp][1] = s1;
        red[w][cp][2] = q0; red[w][cp][3] = q1;
    }
    __syncthreads();
    if (w == 0 && sub == 0){
        #pragma unroll
        for (int ww = 1; ww < 4; ww++){
            s0 += red[ww][cp][0]; s1 += red[ww][cp][1];
            q0 += red[ww][cp][2]; q1 += red[ww][cp][3];
        }
        int c = g*32 + 2*cp;
        atomicAdd(&stats[c],         s0);
        atomicAdd(&stats[c + 1],     s1);
        atomicAdd(&stats[DIM + c],     q0);
        atomicAdd(&stats[DIM + c + 1], q1);
    }
}

// stats -> per-column scale/shift:  sc = rstd*gamma, sh = beta - mu*sc
__global__ void k_bnstat(const float* __restrict__ stats,
                         const float* __restrict__ gamma,
                         const float* __restrict__ beta,
                         float* __restrict__ scsh){
    int c = threadIdx.x;
    float mu  = stats[c] * (1.0f / N_NODES);
    float var = stats[DIM + c] * (1.0f / N_NODES) - mu * mu;
    float sc  = rsqrtf(var + BN_EPS) * gamma[c];
    scsh[c] = sc;
    scsh[DIM + c] = beta[c] - mu * sc;
}

// final-layer BN apply: grouped bf16 in -> standard-layout fp32 out
__global__ __launch_bounds__(256) void k_bn(const uint4* __restrict__ in,
                                            const float* __restrict__ scsh,
                                            float4* __restrict__ outf){
    int i = blockIdx.x * 256 + threadIdx.x;         // 8-bf16 chunk index
    if (i >= N_NODES * DIM / 8) return;
    int row = i >> 4;
    int c = (i * 8) & (DIM - 1);
    int gg = c >> 5, wi = c & 31;
    uint4 raw = in[gg*(N_NODES*4) + row*4 + (wi >> 3)];
    float4 sc0 = *(const float4*)&scsh[c];
    float4 sc1 = *(const float4*)&scsh[c + 4];
    float4 sh0 = *(const float4*)&scsh[DIM + c];
    float4 sh1 = *(const float4*)&scsh[DIM + c + 4];
    unsigned int u[4] = {raw.x, raw.y, raw.z, raw.w};
    float v[8];
    #pragma unroll
    for (int j = 0; j < 4; j++){
        v[2*j]   = bf2f((unsigned short)(u[j] & 0xffff));
        v[2*j+1] = bf2f((unsigned short)(u[j] >> 16));
    }
    float4 r0, r1;
    r0.x = fmaf(v[0], sc0.x, sh0.x);
    r0.y = fmaf(v[1], sc0.y, sh0.y);
    r0.z = fmaf(v[2], sc0.z, sh0.z);
    r0.w = fmaf(v[3], sc0.w, sh0.w);
    r1.x = fmaf(v[4], sc1.x, sh1.x);
    r1.y = fmaf(v[5], sc1.y, sh1.y);
    r1.z = fmaf(v[6], sc1.z, sh1.z);
    r1.w = fmaf(v[7], sc1.w, sh1.w);
    outf[2*i]   = r0;
    outf[2*i+1] = r1;
}

// ---------------- launch ----------------

extern "C" void kernel_launch(void* const* d_in, const int* in_sizes, int n_in,
                              void* d_out, int out_size, void* d_ws, size_t ws_size,
                              hipStream_t stream){
    const float* x   = (const float*)d_in[0];
    const int*   src = (const int*)d_in[1];
    const int*   dst = src + N_EDGES;
    const float* Ws  = (const float*)d_in[2];
    const float* bs  = (const float*)d_in[3];
    const float* gs  = (const float*)d_in[4];
    const float* be  = (const float*)d_in[5];

    char* w = (char*)d_ws;
    int*   degcnt = (int*)(w);                         // 50000 i  [0,200000)
    float* stats  = (float*)(w + 200000);              // 1024 f
    float* scsh   = (float*)(w + 204096);              // 1024 f
    float* dis    = (float*)(w + 208192);              // 50000 f
    int*   rowptr = (int*)(w + 408192);                // 50001 i (pad)
    int*   wptr   = (int*)(w + 608208);                // 50000 i
    int*   bsum   = (int*)(w + 808208);                // 196 i (pad to 809232)
    int2*  epair  = (int2*)(w + 809232);               // 800000 int2 (6.4MB)
    unsigned short* bufA = (unsigned short*)(w + 7209232);   // grouped bf16 (12.8MB)
    unsigned short* hb   = (unsigned short*)(w + 20009232);  // grouped bf16 (12.8MB)
    // total: 32,809,232 bytes

    k_zero<<<(51024 + 255)/256, 256, 0, stream>>>(degcnt, 51024);
    k_count<<<3125, 256, 0, stream>>>(dst, degcnt);
    k_dis<<<196, 256, 0, stream>>>(degcnt, dis);
    k_scan1<<<SCAN_BLOCKS, 256, 0, stream>>>(degcnt, rowptr, bsum);
    k_scan2<<<1, 256, 0, stream>>>(bsum);
    k_scan3<<<SCAN_BLOCKS, 256, 0, stream>>>(bsum, rowptr, wptr);
    k_fill<<<3125, 256, 0, stream>>>(src, dst, dis, wptr, epair);

    for (int L = 0; L < NLAYERS; L++){
        if (L == 0)
            k_gemm<0><<<1563, 256, 0, stream>>>(x, Ws + L*DIM*DIM,
                                                nullptr, hb);
        else
            k_gemm<1><<<1563, 256, 0, stream>>>(bufA, Ws + L*DIM*DIM,
                                                scsh + (L-1)*256, hb);
        k_agg<<<2048, 256, 0, stream>>>(hb, rowptr, epair, dis, bs + L*DIM,
                                        bufA, stats + L*256);
        k_bnstat<<<1, 128, 0, stream>>>(stats + L*256, gs + L*DIM, be + L*DIM,
                                        scsh + L*256);
    }
    k_bn<<<3125, 256, 0, stream>>>((const uint4*)bufA, scsh + 3*256,
                                   (float4*)d_out);
}

// Round 9
// 613.537 us; speedup vs baseline: 1.8341x; 1.0732x over previous
//
#include <hip/hip_runtime.h>

#define N_NODES 50000
#define N_EDGES 800000
#define DIM 128
#define NLAYERS 4
#define BN_EPS 1e-5f
#define SCAN_BLOCKS 196   // ceil(N_NODES/256)
#define WSTRIDE 136       // 128 + 8 bf16 pad (LDS bank decorrelation)

typedef __attribute__((ext_vector_type(8))) short short8;
typedef __attribute__((ext_vector_type(4))) float f32x4;

__device__ __forceinline__ float bf2f(unsigned short u){
    union { unsigned int i; float f; } x; x.i = ((unsigned int)u) << 16; return x.f;
}
__device__ __forceinline__ unsigned short f2bf(float f){
    union { float f; unsigned int i; } x; x.f = f;
    unsigned int lsb = (x.i >> 16) & 1u;
    unsigned int r = x.i + 0x7fffu + lsb;
    return (unsigned short)(r >> 16);
}

// ---------------- prep kernels ----------------

__global__ __launch_bounds__(256) void k_zero(int* __restrict__ p, int n){
    int i = blockIdx.x * 256 + threadIdx.x;
    if (i < n) p[i] = 0;
}

__global__ __launch_bounds__(256) void k_count(const int* __restrict__ dst,
                                               int* __restrict__ degcnt){
    int e = blockIdx.x * 256 + threadIdx.x;
    if (e < N_EDGES) atomicAdd(&degcnt[dst[e]], 1);
}

__global__ __launch_bounds__(256) void k_dis(const int* __restrict__ degcnt,
                                             float* __restrict__ dis){
    int i = blockIdx.x * 256 + threadIdx.x;
    if (i < N_NODES) dis[i] = rsqrtf((float)degcnt[i] + 1.0f);
}

__global__ __launch_bounds__(256) void k_scan1(const int* __restrict__ degcnt,
                                               int* __restrict__ rowptr,
                                               int* __restrict__ bsum){
    __shared__ int tmp[256];
    int t = threadIdx.x;
    int i = blockIdx.x * 256 + t;
    int v = (i < N_NODES) ? degcnt[i] : 0;
    tmp[t] = v;
    __syncthreads();
    #pragma unroll
    for (int off = 1; off < 256; off <<= 1){
        int u = (t >= off) ? tmp[t - off] : 0;
        __syncthreads();
        tmp[t] += u;
        __syncthreads();
    }
    if (i < N_NODES) rowptr[i] = tmp[t] - v;
    if (t == 255) bsum[blockIdx.x] = tmp[255];
}

__global__ __launch_bounds__(256) void k_scan2(int* __restrict__ bsum){
    __shared__ int tmp[256];
    int t = threadIdx.x;
    int v = (t < SCAN_BLOCKS) ? bsum[t] : 0;
    tmp[t] = v;
    __syncthreads();
    #pragma unroll
    for (int off = 1; off < 256; off <<= 1){
        int u = (t >= off) ? tmp[t - off] : 0;
        __syncthreads();
        tmp[t] += u;
        __syncthreads();
    }
    if (t < SCAN_BLOCKS) bsum[t] = tmp[t] - v;
}

__global__ __launch_bounds__(256) void k_scan3(const int* __restrict__ bsum,
                                               int* __restrict__ rowptr,
                                               int* __restrict__ wptr){
    int i = blockIdx.x * 256 + threadIdx.x;
    if (i < N_NODES){
        int r = rowptr[i] + bsum[blockIdx.x];
        rowptr[i] = r; wptr[i] = r;
    }
    if (i == 0) rowptr[N_NODES] = N_EDGES;
}

__global__ __launch_bounds__(256) void k_fill(const int* __restrict__ src,
                                              const int* __restrict__ dst,
                                              const float* __restrict__ dis,
                                              int* __restrict__ wptr,
                                              int2* __restrict__ epair){
    int e = blockIdx.x * 256 + threadIdx.x;
    if (e < N_EDGES){
        int s = src[e], d = dst[e];
        float w = dis[s] * dis[d];
        int p = atomicAdd(&wptr[d], 1);
        int2 pr; pr.x = s; pr.y = __float_as_int(w);
        epair[p] = pr;
    }
}

// x fp32 [N,128] -> grouped bf16 xg[g][node][32]
__global__ __launch_bounds__(256) void k_cvt(const float* __restrict__ x,
                                             unsigned short* __restrict__ xg){
    int i = blockIdx.x * 256 + threadIdx.x;   // 8-col chunk id, 0..799999
    if (i >= N_NODES * 16) return;
    int row = i >> 4;
    int c = (i & 15) * 8;
    float4 v0 = *(const float4*)&x[row*DIM + c];
    float4 v1 = *(const float4*)&x[row*DIM + c + 4];
    int g = c >> 5, wi = c & 31;
    ushort4 o0, o1;
    o0.x = f2bf(v0.x); o0.y = f2bf(v0.y); o0.z = f2bf(v0.z); o0.w = f2bf(v0.w);
    o1.x = f2bf(v1.x); o1.y = f2bf(v1.y); o1.z = f2bf(v1.z); o1.w = f2bf(v1.w);
    unsigned short* p = &xg[(size_t)g*N_NODES*32 + (size_t)row*32 + wi];
    *(ushort4*)p = o0;
    *(ushort4*)(p + 4) = o1;
}

// W' = diag(sc)*W folded; write W'^T (c-major) as bf16 hi/lo split.
template<bool HAS>
__global__ __launch_bounds__(256) void k_wprep(const float* __restrict__ W,
                                               const float* __restrict__ scsh,
                                               unsigned short* __restrict__ wthi,
                                               unsigned short* __restrict__ wtlo){
    int idx = blockIdx.x * 256 + threadIdx.x;   // 0..16383
    int c = idx >> 7, k = idx & 127;
    float v = W[k*DIM + c];
    if (HAS) v *= scsh[k];
    unsigned short hi = f2bf(v);
    float lo = v - bf2f(hi);
    wthi[c*DIM + k] = hi;
    wtlo[c*DIM + k] = f2bf(lo);
}

// bias2[c] = sum_k sh[k] * W[k][c]   (sh = scsh[DIM..]); zero if !HAS
template<bool HAS>
__global__ __launch_bounds__(128) void k_wbias(const float* __restrict__ W,
                                               const float* __restrict__ scsh,
                                               float* __restrict__ bias2){
    int c = threadIdx.x;
    float acc = 0.f;
    if (HAS){
        #pragma unroll 4
        for (int k = 0; k < DIM; k++)
            acc = fmaf(scsh[DIM + k], W[k*DIM + c], acc);
    }
    bias2[c] = acc;
}

// ---------------- per-layer kernels ----------------
// Grouped feature layout: t[g][node][32 cols], g = col>>5 (3.2MB/slice).

// MFMA GEMM: h = z @ W' + bias2.  z grouped bf16, W'^T hi/lo bf16, h grouped bf16.
// 64 rows/block, 4 waves; wave = 16 rows x 128 cols = 8 mfma 16x16x32 tiles, K=128.
__global__ __launch_bounds__(256) void k_gemm(const unsigned short* __restrict__ zg,
                                              const unsigned short* __restrict__ wthi,
                                              const unsigned short* __restrict__ wtlo,
                                              const float* __restrict__ bias2,
                                              unsigned short* __restrict__ hb){
    __shared__ short whi[DIM * WSTRIDE];       // 34816 B
    __shared__ short wlo[DIM * WSTRIDE];       // 34816 B
    int tid = threadIdx.x;

    // stage W'^T (dense [c][128]) -> LDS (padded [c][136]); 2048 uint4 chunks each
    {
        const uint4* gh = (const uint4*)wthi;
        const uint4* gl = (const uint4*)wtlo;
        #pragma unroll
        for (int it = 0; it < 8; it++){
            int ch = tid + 256*it;             // 0..2047
            int c = ch >> 4, k8 = ch & 15;
            int off = c*WSTRIDE + k8*8;
            *(uint4*)&whi[off] = gh[ch];
            *(uint4*)&wlo[off] = gl[ch];
        }
    }
    __syncthreads();

    int lane = tid & 63;
    int wv   = tid >> 6;
    int m = lane & 15;                         // row in tile / col in tile
    int q = lane >> 4;                         // quad
    int row0 = blockIdx.x * 64 + wv * 16;
    int arow = row0 + m;
    bool avalid = arow < N_NODES;

    f32x4 acc[8];
    #pragma unroll
    for (int t = 0; t < 8; t++) acc[t] = (f32x4){0.f, 0.f, 0.f, 0.f};

    #pragma unroll
    for (int g = 0; g < 4; g++){               // k-step = feature group
        short8 a = {0,0,0,0,0,0,0,0};
        if (avalid)
            a = *(const short8*)&zg[(size_t)g*N_NODES*32 + (size_t)arow*32 + q*8];
        #pragma unroll
        for (int t = 0; t < 8; t++){
            int col = t*16 + m;
            int off = col*WSTRIDE + g*32 + q*8;
            short8 bh = *(const short8*)&whi[off];
            short8 bl = *(const short8*)&wlo[off];
            acc[t] = __builtin_amdgcn_mfma_f32_16x16x32_bf16(a, bh, acc[t], 0, 0, 0);
            acc[t] = __builtin_amdgcn_mfma_f32_16x16x32_bf16(a, bl, acc[t], 0, 0, 0);
        }
    }

    // epilogue: D[row=(q*4+r)][col=t*16+m] + bias2 -> grouped bf16
    #pragma unroll
    for (int t = 0; t < 8; t++){
        int colg = t*16 + m;
        float bz = bias2[colg];
        size_t base = (size_t)(t >> 1)*N_NODES*32 + (t & 1)*16 + m;
        #pragma unroll
        for (int r = 0; r < 4; r++){
            int row = row0 + q*4 + r;
            if (row < N_NODES)
                hb[base + (size_t)row*32] = f2bf(acc[t][r] + bz);
        }
    }
}

// CSR aggregation + bias + ReLU + per-column stats, feature-group partitioned.
// group = blockIdx&3. 16 lanes/edge (ushort2 cols), 4 edges/load, x4 unrolled.
__global__ __launch_bounds__(256) void k_agg(const unsigned short* __restrict__ h,
                                             const int* __restrict__ rowptr,
                                             const int2* __restrict__ epair,
                                             const float* __restrict__ dis,
                                             const float* __restrict__ bias,
                                             unsigned short* __restrict__ out,
                                             float* __restrict__ stats){
    int lane = threadIdx.x & 63;
    int w    = threadIdx.x >> 6;
    int g    = blockIdx.x & 3;
    int sub  = lane >> 4;
    int cp   = lane & 15;
    const ushort2* hg = (const ushort2*)(h + (size_t)g * N_NODES * 32);
    ushort2* og = (ushort2*)(out + (size_t)g * N_NODES * 32);
    float b0 = bias[g*32 + 2*cp], b1 = bias[g*32 + 2*cp + 1];
    float s0 = 0.f, s1 = 0.f, q0 = 0.f, q1 = 0.f;
    int bg = blockIdx.x >> 2;
    int nstride = (gridDim.x >> 2) * 4;

    for (int node = bg*4 + w; node < N_NODES; node += nstride){
        float di = dis[node];
        int e0 = rowptr[node], e1 = rowptr[node + 1];
        float pa0 = 0.f, pa1 = 0.f, pb0 = 0.f, pb1 = 0.f;
        float pc0 = 0.f, pc1 = 0.f, pd0 = 0.f, pd1 = 0.f;
        if (sub == 0){
            ushort2 hv = hg[node*16 + cp];
            float dii = di * di;
            pa0 = bf2f(hv.x) * dii; pa1 = bf2f(hv.y) * dii;
        }
        int e = e0;
        for (; e + 16 <= e1; e += 16){
            int2 P0 = epair[e + sub];
            int2 P1 = epair[e + 4 + sub];
            int2 P2 = epair[e + 8 + sub];
            int2 P3 = epair[e + 12 + sub];
            ushort2 X0 = hg[P0.x*16 + cp];
            ushort2 X1 = hg[P1.x*16 + cp];
            ushort2 X2 = hg[P2.x*16 + cp];
            ushort2 X3 = hg[P3.x*16 + cp];
            float w0 = __int_as_float(P0.y), w1 = __int_as_float(P1.y);
            float w2 = __int_as_float(P2.y), w3 = __int_as_float(P3.y);
            pa0 = fmaf(bf2f(X0.x), w0, pa0); pa1 = fmaf(bf2f(X0.y), w0, pa1);
            pb0 = fmaf(bf2f(X1.x), w1, pb0); pb1 = fmaf(bf2f(X1.y), w1, pb1);
            pc0 = fmaf(bf2f(X2.x), w2, pc0); pc1 = fmaf(bf2f(X2.y), w2, pc1);
            pd0 = fmaf(bf2f(X3.x), w3, pd0); pd1 = fmaf(bf2f(X3.y), w3, pd1);
        }
        for (; e + 8 <= e1; e += 8){
            int2 P0 = epair[e + sub];
            int2 P1 = epair[e + 4 + sub];
            ushort2 X0 = hg[P0.x*16 + cp];
            ushort2 X1 = hg[P1.x*16 + cp];
            float w0 = __int_as_float(P0.y), w1 = __int_as_float(P1.y);
            pa0 = fmaf(bf2f(X0.x), w0, pa0); pa1 = fmaf(bf2f(X0.y), w0, pa1);
            pb0 = fmaf(bf2f(X1.x), w1, pb0); pb1 = fmaf(bf2f(X1.y), w1, pb1);
        }
        for (; e < e1; e += 4){
            int ide = e + sub;
            int2 pr = (ide < e1) ? epair[ide] : make_int2(0, 0);
            ushort2 xv = hg[pr.x*16 + cp];
            float we = __int_as_float(pr.y);
            pa0 = fmaf(bf2f(xv.x), we, pa0);
            pa1 = fmaf(bf2f(xv.y), we, pa1);
        }
        float r0 = (pa0 + pb0) + (pc0 + pd0);
        float r1 = (pa1 + pb1) + (pc1 + pd1);
        r0 += __shfl_xor(r0, 16); r1 += __shfl_xor(r1, 16);
        r0 += __shfl_xor(r0, 32); r1 += __shfl_xor(r1, 32);
        if (sub == 0){
            float a0 = fmaxf(r0 + b0, 0.f);
            float a1 = fmaxf(r1 + b1, 0.f);
            ushort2 ov; ov.x = f2bf(a0); ov.y = f2bf(a1);
            og[node*16 + cp] = ov;
            s0 += a0; s1 += a1; q0 += a0*a0; q1 += a1*a1;
        }
    }

    __shared__ float red[4][16][4];
    if (sub == 0){
        red[w][cp][0] = s0; red[w][cp][1] = s1;
        red[w][cp][2] = q0; red[w][cp][3] = q1;
    }
    __syncthreads();
    if (w == 0 && sub == 0){
        #pragma unroll
        for (int ww = 1; ww < 4; ww++){
            s0 += red[ww][cp][0]; s1 += red[ww][cp][1];
            q0 += red[ww][cp][2]; q1 += red[ww][cp][3];
        }
        int c = g*32 + 2*cp;
        atomicAdd(&stats[c],         s0);
        atomicAdd(&stats[c + 1],     s1);
        atomicAdd(&stats[DIM + c],     q0);
        atomicAdd(&stats[DIM + c + 1], q1);
    }
}

// stats -> per-column scale/shift:  sc = rstd*gamma, sh = beta - mu*sc
__global__ void k_bnstat(const float* __restrict__ stats,
                         const float* __restrict__ gamma,
                         const float* __restrict__ beta,
                         float* __restrict__ scsh){
    int c = threadIdx.x;
    float mu  = stats[c] * (1.0f / N_NODES);
    float var = stats[DIM + c] * (1.0f / N_NODES) - mu * mu;
    float sc  = rsqrtf(var + BN_EPS) * gamma[c];
    scsh[c] = sc;
    scsh[DIM + c] = beta[c] - mu * sc;
}

// final-layer BN apply: grouped bf16 in -> standard-layout fp32 out
__global__ __launch_bounds__(256) void k_bn(const uint4* __restrict__ in,
                                            const float* __restrict__ scsh,
                                            float4* __restrict__ outf){
    int i = blockIdx.x * 256 + threadIdx.x;         // 8-bf16 chunk index
    if (i >= N_NODES * DIM / 8) return;
    int row = i >> 4;
    int c = (i * 8) & (DIM - 1);
    int gg = c >> 5, wi = c & 31;
    uint4 raw = in[gg*(N_NODES*4) + row*4 + (wi >> 3)];
    float4 sc0 = *(const float4*)&scsh[c];
    float4 sc1 = *(const float4*)&scsh[c + 4];
    float4 sh0 = *(const float4*)&scsh[DIM + c];
    float4 sh1 = *(const float4*)&scsh[DIM + c + 4];
    unsigned int u[4] = {raw.x, raw.y, raw.z, raw.w};
    float v[8];
    #pragma unroll
    for (int j = 0; j < 4; j++){
        v[2*j]   = bf2f((unsigned short)(u[j] & 0xffff));
        v[2*j+1] = bf2f((unsigned short)(u[j] >> 16));
    }
    float4 r0, r1;
    r0.x = fmaf(v[0], sc0.x, sh0.x);
    r0.y = fmaf(v[1], sc0.y, sh0.y);
    r0.z = fmaf(v[2], sc0.z, sh0.z);
    r0.w = fmaf(v[3], sc0.w, sh0.w);
    r1.x = fmaf(v[4], sc1.x, sh1.x);
    r1.y = fmaf(v[5], sc1.y, sh1.y);
    r1.z = fmaf(v[6], sc1.z, sh1.z);
    r1.w = fmaf(v[7], sc1.w, sh1.w);
    outf[2*i]   = r0;
    outf[2*i+1] = r1;
}

// ---------------- launch ----------------

extern "C" void kernel_launch(void* const* d_in, const int* in_sizes, int n_in,
                              void* d_out, int out_size, void* d_ws, size_t ws_size,
                              hipStream_t stream){
    const float* x   = (const float*)d_in[0];
    const int*   src = (const int*)d_in[1];
    const int*   dst = src + N_EDGES;
    const float* Ws  = (const float*)d_in[2];
    const float* bs  = (const float*)d_in[3];
    const float* gs  = (const float*)d_in[4];
    const float* be  = (const float*)d_in[5];

    char* w = (char*)d_ws;
    int*   degcnt = (int*)(w);                         // 50000 i  [0,200000)
    float* stats  = (float*)(w + 200000);              // 1024 f
    float* scsh   = (float*)(w + 204096);              // 1024 f
    float* dis    = (float*)(w + 208192);              // 50000 f
    int*   rowptr = (int*)(w + 408192);                // 50001 i (pad)
    int*   wptr   = (int*)(w + 608208);                // 50000 i
    int*   bsum   = (int*)(w + 808208);                // 196 i (pad)
    float* bias2  = (float*)(w + 809232);              // 128 f
    unsigned short* wthi = (unsigned short*)(w + 809744);   // 16384 bf16 (32KB)
    unsigned short* wtlo = (unsigned short*)(w + 842512);   // 16384 bf16 (32KB)
    int2*  epair  = (int2*)(w + 875280);               // 800000 int2 (6.4MB)
    unsigned short* xg   = (unsigned short*)(w + 7275280);   // grouped bf16 (12.8MB)
    unsigned short* bufA = (unsigned short*)(w + 20075280);  // grouped bf16 (12.8MB)
    unsigned short* hb   = (unsigned short*)(w + 32875280);  // grouped bf16 (12.8MB)
    // total: 45,675,280 bytes

    k_zero<<<(51024 + 255)/256, 256, 0, stream>>>(degcnt, 51024);
    k_count<<<3125, 256, 0, stream>>>(dst, degcnt);
    k_dis<<<196, 256, 0, stream>>>(degcnt, dis);
    k_scan1<<<SCAN_BLOCKS, 256, 0, stream>>>(degcnt, rowptr, bsum);
    k_scan2<<<1, 256, 0, stream>>>(bsum);
    k_scan3<<<SCAN_BLOCKS, 256, 0, stream>>>(bsum, rowptr, wptr);
    k_fill<<<3125, 256, 0, stream>>>(src, dst, dis, wptr, epair);
    k_cvt<<<3125, 256, 0, stream>>>(x, xg);

    for (int L = 0; L < NLAYERS; L++){
        const float* Wl = Ws + L*DIM*DIM;
        if (L == 0){
            k_wprep<false><<<64, 256, 0, stream>>>(Wl, nullptr, wthi, wtlo);
            k_wbias<false><<<1, 128, 0, stream>>>(Wl, nullptr, bias2);
        } else {
            k_wprep<true><<<64, 256, 0, stream>>>(Wl, scsh + (L-1)*256, wthi, wtlo);
            k_wbias<true><<<1, 128, 0, stream>>>(Wl, scsh + (L-1)*256, bias2);
        }
        const unsigned short* zin = (L == 0) ? xg : bufA;
        k_gemm<<<(N_NODES + 63)/64, 256, 0, stream>>>(zin, wthi, wtlo, bias2, hb);
        k_agg<<<2048, 256, 0, stream>>>(hb, rowptr, epair, dis, bs + L*DIM,
                                        bufA, stats + L*256);
        k_bnstat<<<1, 128, 0, stream>>>(stats + L*256, gs + L*DIM, be + L*DIM,
                                        scsh + L*256);
    }
    k_bn<<<3125, 256, 0, stream>>>((const uint4*)bufA, scsh + 3*256,
                                   (float4*)d_out);
}